// Round 10
// baseline (141.499 us; speedup 1.0000x reference)
//
#include <hip/hip_runtime.h>

#define N 12288
#define M (2 * N)          // keys (t_j) + queries (-s_i)
#define DIN 128
#define DOUT 64
#define NBIN 8192
#define BSHIFT 19          // 32 - log2(NBIN)
#define NCHUNK 384         // M / 64
#define K1BLKS 768         // N / 16

// monotone float -> ordered u32 (order-preserving bit transform)
__device__ __forceinline__ unsigned f_ord(float x) {
    unsigned b = __float_as_uint(x);
    return (b & 0x80000000u) ? ~b : (b | 0x80000000u);
}
__device__ __forceinline__ float ord_f(unsigned u) {
    unsigned b = (u & 0x80000000u) ? (u & 0x7FFFFFFFu) : ~u;
    return __uint_as_float(b);
}
__device__ __forceinline__ int t_bin(float x) { return (int)(f_ord(x) >> BSHIFT); }

struct Args {
    const float *h, *W, *a;
    float *Wh, *s, *t, *tblkmax, *Thdr;
    unsigned long long *vals64;     // (ordered(val)<<32)|pi — unique total order
    float *tfin;
    int *idfin, *binstart;
    float2 *VU, *sc;                // per-chunk column/scalar sums {v,u}
    float *out;
};

// ---------- K1: Wh = h@W, s, t, per-block max(t) (768 blocks x 256) ---------
// 1 row x 4 cols per thread -> 3072 waves (3/SIMD, 12/CU); LDS 41 KB/block;
// h-tile stride padded 32->33 float4 (bank-conflict break). Measured round 9:
// pipeline 132.9 -> 127.1 with this retile (k1 < 40 µs, below the fills).
__global__ __launch_bounds__(256) void k1_gemm(Args A) {
    __shared__ float4 sm4[2576];               // 41 KB: W 2048 + h 16x33
    __shared__ float wmax[4];
    int tid = threadIdx.x, lane = tid & 63, wave = tid >> 6, blk = blockIdx.x;
    float4* Ws4 = sm4;                         // W[k][c4]  (2048)
    float4* hs4 = sm4 + 2048;                  // h[r][k4]  stride 33
    const float4* W4 = (const float4*)A.W;
    #pragma unroll
    for (int e = tid; e < 2048; e += 256) Ws4[e] = W4[e];
    int row0 = blk * 16;
    const float4* h4 = (const float4*)(A.h + (size_t)row0 * DIN);
    #pragma unroll
    for (int e = tid; e < 512; e += 256) hs4[(e >> 5) * 33 + (e & 31)] = h4[e];
    __syncthreads();
    int c0 = tid & 15, r = tid >> 4;           // 16 rows x 16 col-groups
    float4 acc = make_float4(0.f, 0.f, 0.f, 0.f);
    #pragma unroll 4
    for (int kk = 0; kk < 32; ++kk) {
        float4 hv = hs4[r * 33 + kk];          // broadcast among 16 lanes
        float4 w0 = Ws4[(4 * kk + 0) * 16 + c0];
        float4 w1 = Ws4[(4 * kk + 1) * 16 + c0];
        float4 w2 = Ws4[(4 * kk + 2) * 16 + c0];
        float4 w3 = Ws4[(4 * kk + 3) * 16 + c0];
        acc.x = fmaf(hv.x, w0.x, acc.x); acc.y = fmaf(hv.x, w0.y, acc.y);
        acc.z = fmaf(hv.x, w0.z, acc.z); acc.w = fmaf(hv.x, w0.w, acc.w);
        acc.x = fmaf(hv.y, w1.x, acc.x); acc.y = fmaf(hv.y, w1.y, acc.y);
        acc.z = fmaf(hv.y, w1.z, acc.z); acc.w = fmaf(hv.y, w1.w, acc.w);
        acc.x = fmaf(hv.z, w2.x, acc.x); acc.y = fmaf(hv.z, w2.y, acc.y);
        acc.z = fmaf(hv.z, w2.z, acc.z); acc.w = fmaf(hv.z, w2.w, acc.w);
        acc.x = fmaf(hv.w, w3.x, acc.x); acc.y = fmaf(hv.w, w3.y, acc.y);
        acc.z = fmaf(hv.w, w3.z, acc.z); acc.w = fmaf(hv.w, w3.w, acc.w);
    }
    int row = row0 + r;
    ((float4*)A.Wh)[(size_t)row * 16 + c0] = acc;
    float4 a1 = ((const float4*)A.a)[c0];
    float4 a2 = ((const float4*)A.a)[16 + c0];
    float sv = acc.x * a1.x + acc.y * a1.y + acc.z * a1.z + acc.w * a1.w;
    float tv = acc.x * a2.x + acc.y * a2.y + acc.z * a2.z + acc.w * a2.w;
    #pragma unroll
    for (int off = 8; off; off >>= 1) {        // reduce over 16-lane row group
        sv += __shfl_xor(sv, off, 64);
        tv += __shfl_xor(tv, off, 64);
    }
    if (c0 == 0) { A.s[row] = sv; A.t[row] = tv; }
    float tmax = tv;                           // every lane has its row's tv
    tmax = fmaxf(tmax, __shfl_xor(tmax, 16, 64));
    tmax = fmaxf(tmax, __shfl_xor(tmax, 32, 64));
    if (lane == 0) wmax[wave] = tmax;
    __syncthreads();
    if (tid == 0)
        A.tblkmax[blk] = fmaxf(fmaxf(wmax[0], wmax[1]), fmaxf(wmax[2], wmax[3]));
}

// ---------- K2: LDS hist + pre-hist + scan + T + packed-key scatter ----------
__global__ __launch_bounds__(1024) void k2_sort(Args A) {
    __shared__ int hist[NBIN];                  // 32 KB
    __shared__ int pre[NBIN];                   // 32 KB
    __shared__ int wtot[16];
    __shared__ float fmax_[16];
    int tid = threadIdx.x, lane = tid & 63, wave = tid >> 6, blk = blockIdx.x;
    #pragma unroll
    for (int e = tid; e < NBIN; e += 1024) { hist[e] = 0; pre[e] = 0; }
    __syncthreads();
    #pragma unroll 4
    for (int e = tid; e < M; e += 1024) {
        float v = (e < N) ? A.t[e] : -A.s[e - N];
        atomicAdd(&hist[t_bin(v)], 1);
    }
    int my0 = blk * 1024;
    #pragma unroll 4
    for (int e = tid; e < my0; e += 1024) {
        float v = (e < N) ? A.t[e] : -A.s[e - N];
        atomicAdd(&pre[t_bin(v)], 1);
    }
    __syncthreads();
    int b0 = tid * 8;
    int c8[8]; int sum = 0;
    #pragma unroll
    for (int g = 0; g < 8; ++g) { c8[g] = sum; sum += hist[b0 + g]; }
    int inc = sum;
    #pragma unroll
    for (int off = 1; off < 64; off <<= 1) {
        int nb = __shfl_up(inc, off, 64);
        if (lane >= off) inc += nb;
    }
    if (lane == 63) wtot[wave] = inc;
    __syncthreads();
    int wbase = 0;
    #pragma unroll
    for (int w = 0; w < 16; ++w) wbase += (w < wave) ? wtot[w] : 0;
    int tstart = wbase + inc - sum;
    #pragma unroll
    for (int g = 0; g < 8; ++g) {
        int bs = tstart + c8[g];
        hist[b0 + g] = bs;
        pre[b0 + g] += bs;
        A.binstart[b0 + g] = bs;                // benign duplicate across blocks
    }
    if (tid == 0 && blk == 0) A.binstart[NBIN] = M;
    float m = (tid < K1BLKS) ? A.tblkmax[tid] : -3.4e38f;   // 768 k1 blocks
    #pragma unroll
    for (int off = 32; off; off >>= 1) m = fmaxf(m, __shfl_xor(m, off, 64));
    if (lane == 0) fmax_[wave] = m;
    __syncthreads();
    if (tid == 0) {
        float mm = fmax_[0];
        #pragma unroll
        for (int w = 1; w < 16; ++w) mm = fmaxf(mm, fmax_[w]);
        A.Thdr[0] = mm;
    }
    __syncthreads();
    {   // exactly one item per thread (slice == blockDim)
        int e = my0 + tid;
        float v = (e < N) ? A.t[e] : -A.s[e - N];
        int pi = (e < N) ? (e + N) : (e - N);   // queries sort before equal keys
        int pos = atomicAdd(&pre[t_bin(v)], 1);
        A.vals64[pos] = ((unsigned long long)f_ord(v) << 32) | (unsigned)pi;
    }
}

// ---------- K3: exact in-bin rank, 4 THREADS per position ----------
__global__ __launch_bounds__(256) void k3_rank(Args A) {
    __shared__ int parts[256];
    int tid = threadIdx.x;
    int li = tid & 63, sub = tid >> 6;
    int p = blockIdx.x * 64 + li;
    unsigned long long kp = A.vals64[p];
    int b = (int)(kp >> (32 + BSHIFT));
    int lo = A.binstart[b], hi = A.binstart[b + 1];
    int len = hi - lo;
    int qlen = (len + 3) >> 2;
    int qlo = lo + sub * qlen;
    if (qlo > hi) qlo = hi;
    int qhi = qlo + qlen;
    if (qhi > hi) qhi = hi;
    int cnt = 0;
    int q = qlo;
    while (q < qhi && (q & 3)) cnt += (int)(A.vals64[q++] < kp);
    int bend = q + ((qhi - q) & ~3);
    #pragma unroll 2
    for (; q < bend; q += 4) {
        ulonglong2 u0 = *(const ulonglong2*)&A.vals64[q];
        ulonglong2 u1 = *(const ulonglong2*)&A.vals64[q + 2];
        cnt += (int)(u0.x < kp) + (int)(u0.y < kp)
             + (int)(u1.x < kp) + (int)(u1.y < kp);
    }
    while (q < qhi) cnt += (int)(A.vals64[q++] < kp);
    parts[sub * 64 + li] = cnt;
    __syncthreads();
    if (sub == 0) {
        int tot = parts[li] + parts[64 + li] + parts[128 + li] + parts[192 + li];
        int pi = (int)(unsigned)(kp & 0xffffffffu);
        A.tfin[lo + tot] = ord_f((unsigned)(kp >> 32));
        A.idfin[lo + tot] = (pi >= N) ? (pi - N) : (pi + N);
    }
}

// ---------- K4: per-chunk (64 sorted items) key-sums (96 blocks x 256) ------
__global__ __launch_bounds__(256) void k4_sums(Args A) {
    int tid = threadIdx.x, wave = tid >> 6, lane = tid & 63;
    int c = blockIdx.x * 4 + wave;              // 384 chunks
    float T = A.Thdr[0];
    float myval = A.tfin[c * 64 + lane];
    int myid = A.idfin[c * 64 + lane];
    float x[64];
    #pragma unroll
    for (int k = 0; k < 64; ++k) {              // 64 independent gathers
        int uid = __shfl(myid, k, 64);
        x[k] = (uid < N) ? A.Wh[(size_t)uid * DOUT + lane] : 0.f;
    }
    float av = 0.f, au = 0.f, svs = 0.f, sus = 0.f;
    #pragma unroll
    for (int k = 0; k < 64; ++k) {
        int uid = __shfl(myid, k, 64);
        if (uid < N) {
            float uval = __shfl(myval, k, 64);
            float wv = expf(0.2f * (uval - T));
            float w2 = wv * wv, w4 = w2 * w2;
            float wu = w4 * wv;                 // exp(uval-T) = wv^5
            av = fmaf(wv, x[k], av); au = fmaf(wu, x[k], au);
            svs += wv; sus += wu;
        }
    }
    A.VU[c * 64 + lane] = make_float2(av, au);
    if (lane == 0) A.sc[c] = make_float2(svs, sus);
}

// ---------- K5: self-computed bases (replaces k4b dispatch) + apply ---------
// VU/sc are complete when this DISPATCH begins (no intra-kernel sync needed).
// Each wave derives its own forward-exclusive base and the grand totals:
//  - scalar prefix/totals: lane-split over 384 chunks + butterfly reduce
//  - column prefix/totals: 16-wide explicitly-batched loads (ILP), predicated
//    accumulate for j < c. Extra traffic: 384 waves x 390 float2 ≈ 2.4 MB L2.
// Numerics identical to rounds 3-5 (passed, absmax 0.0078125).
__global__ __launch_bounds__(256) void k5_apply(Args A) {
    int tid = threadIdx.x, wave = tid >> 6, lane = tid & 63;
    int c = blockIdx.x * 4 + wave;              // 384 chunks
    float T = A.Thdr[0];
    float myval = A.tfin[c * 64 + lane];
    int myid = A.idfin[c * 64 + lane];
    float x[64];
    #pragma unroll
    for (int k = 0; k < 64; ++k) {              // 64 independent gathers
        int uid = __shfl(myid, k, 64);
        x[k] = (uid < N) ? A.Wh[(size_t)uid * DOUT + lane] : 0.f;
    }
    // ---- scalar prefix (j<c) and total: lane-split, coalesced -------------
    float psv = 0.f, psu = 0.f, tsu = 0.f;
    #pragma unroll
    for (int b = 0; b < 6; ++b) {
        int j = b * 64 + lane;                  // covers exactly 0..383
        float2 q = A.sc[j];
        tsu += q.y;
        if (j < c) { psv += q.x; psu += q.y; }
    }
    #pragma unroll
    for (int off = 32; off; off >>= 1) {
        psv += __shfl_xor(psv, off, 64);
        psu += __shfl_xor(psu, off, 64);
        tsu += __shfl_xor(tsu, off, 64);
    }
    // ---- column prefix (j<c) and total: 16-wide batched for ILP -----------
    float bv = 0.f, bu = 0.f, tu = 0.f;
    for (int j0 = 0; j0 < NCHUNK; j0 += 16) {
        float2 aa[16];
        #pragma unroll
        for (int k = 0; k < 16; ++k) aa[k] = A.VU[(size_t)(j0 + k) * 64 + lane];
        #pragma unroll
        for (int k = 0; k < 16; ++k) {
            tu += aa[k].y;
            if (j0 + k < c) { bv += aa[k].x; bu += aa[k].y; }
        }
    }
    // ---- apply sweep ------------------------------------------------------
    float rv = bv, ru = bu, rvs = psv, rus = psu;
    float tus = tsu;
    #pragma unroll
    for (int k = 0; k < 64; ++k) {
        float uval = __shfl(myval, k, 64);
        int uid = __shfl(myid, k, 64);
        if (uid < N) {                          // key: advance running sums
            float wv = expf(0.2f * (uval - T));
            float w2 = wv * wv, w4 = w2 * w2;
            float wu = w4 * wv;                 // exp(uval-T)
            rv = fmaf(wv, x[k], rv); ru = fmaf(wu, x[k], ru);
            rvs += wv; rus += wu;
        } else {                                // query: emit output row
            int i = uid - N;
            float si = -uval;
            float xx = si + T;
            float mm = fmaxf(xx, 0.2f * xx);
            float cp_ = expf(xx - mm);
            float cn_ = expf(0.2f * xx - mm);
            float num = cn_ * rv + cp_ * (tu - ru);
            float den = cn_ * rvs + cp_ * (tus - rus);
            float r = num / den;
            A.out[(size_t)i * DOUT + lane] = r > 0.f ? r : expm1f(r);
        }
    }
}

extern "C" void kernel_launch(void* const* d_in, const int* in_sizes, int n_in,
                              void* d_out, int out_size, void* d_ws, size_t ws_size,
                              hipStream_t stream) {
    float* ws = (float*)d_ws;
    size_t o = 0;
    Args A;
    A.h = (const float*)d_in[0];
    A.W = (const float*)d_in[1];
    A.a = (const float*)d_in[2];
    A.out = (float*)d_out;
    A.Wh      = ws + o; o += (size_t)N * DOUT;
    A.s       = ws + o; o += N;
    A.t       = ws + o; o += N;
    A.tblkmax = ws + o; o += K1BLKS;            // 768 k1 blocks
    A.Thdr    = ws + o; o += 16;                // keeps o 16B-aligned
    A.vals64  = (unsigned long long*)(ws + o); o += 2 * (size_t)M;
    A.tfin    = ws + o; o += M;
    A.VU      = (float2*)(ws + o); o += 2 * (size_t)NCHUNK * DOUT;
    A.sc      = (float2*)(ws + o); o += 2 * NCHUNK;
    A.idfin    = (int*)(ws + o); o += M;
    A.binstart = (int*)(ws + o); o += NBIN + 16;
    // ~4 MB total; no initialization required

    k1_gemm <<<K1BLKS, 256, 0, stream>>>(A);
    k2_sort <<<24, 1024, 0, stream>>>(A);
    k3_rank <<<M / 64, 256, 0, stream>>>(A);
    k4_sums <<<NCHUNK / 4, 256, 0, stream>>>(A);
    k5_apply<<<NCHUNK / 4, 256, 0, stream>>>(A);
}

// Round 11
// 124.142 us; speedup vs baseline: 1.1398x; 1.1398x over previous
//
#include <hip/hip_runtime.h>

#define N 12288
#define M (2 * N)          // keys (t_j) + queries (-s_i)
#define DIN 128
#define DOUT 64
#define NBIN 8192
#define BSHIFT 19          // 32 - log2(NBIN)
#define NCHUNK 384         // M / 64
#define K1BLKS 768         // N / 16

// monotone float -> ordered u32 (order-preserving bit transform)
__device__ __forceinline__ unsigned f_ord(float x) {
    unsigned b = __float_as_uint(x);
    return (b & 0x80000000u) ? ~b : (b | 0x80000000u);
}
__device__ __forceinline__ float ord_f(unsigned u) {
    unsigned b = (u & 0x80000000u) ? (u & 0x7FFFFFFFu) : ~u;
    return __uint_as_float(b);
}
__device__ __forceinline__ int t_bin(float x) { return (int)(f_ord(x) >> BSHIFT); }

struct Args {
    const float *h, *W, *a;
    float *Wh, *s, *t, *tblkmax, *Thdr;
    unsigned long long *vals64;     // (ordered(val)<<32)|pi — unique total order
    float *tfin;
    int *idfin, *binstart;
    float2 *VU, *sc;                // per-chunk column/scalar sums {v,u}
    float2 *baseVU, *basesc;        // forward-exclusive prefixes
    float *utot, *utots;            // U totals (suffix = total - prefix)
    float *out;
};

// ---------- K1: Wh = h@W, s, t, per-block max(t) (768 blocks x 256) ---------
// 1 row x 4 cols per thread -> 3072 waves (3/SIMD, 12/CU); LDS 41 KB/block;
// h-tile stride padded 32->33 float4. Proven in round 9 (132.9 -> 127.1).
__global__ __launch_bounds__(256) void k1_gemm(Args A) {
    __shared__ float4 sm4[2576];               // 41 KB: W 2048 + h 16x33
    __shared__ float wmax[4];
    int tid = threadIdx.x, lane = tid & 63, wave = tid >> 6, blk = blockIdx.x;
    float4* Ws4 = sm4;                         // W[k][c4]  (2048)
    float4* hs4 = sm4 + 2048;                  // h[r][k4]  stride 33
    const float4* W4 = (const float4*)A.W;
    #pragma unroll
    for (int e = tid; e < 2048; e += 256) Ws4[e] = W4[e];
    int row0 = blk * 16;
    const float4* h4 = (const float4*)(A.h + (size_t)row0 * DIN);
    #pragma unroll
    for (int e = tid; e < 512; e += 256) hs4[(e >> 5) * 33 + (e & 31)] = h4[e];
    __syncthreads();
    int c0 = tid & 15, r = tid >> 4;           // 16 rows x 16 col-groups
    float4 acc = make_float4(0.f, 0.f, 0.f, 0.f);
    #pragma unroll 4
    for (int kk = 0; kk < 32; ++kk) {
        float4 hv = hs4[r * 33 + kk];          // broadcast among 16 lanes
        float4 w0 = Ws4[(4 * kk + 0) * 16 + c0];
        float4 w1 = Ws4[(4 * kk + 1) * 16 + c0];
        float4 w2 = Ws4[(4 * kk + 2) * 16 + c0];
        float4 w3 = Ws4[(4 * kk + 3) * 16 + c0];
        acc.x = fmaf(hv.x, w0.x, acc.x); acc.y = fmaf(hv.x, w0.y, acc.y);
        acc.z = fmaf(hv.x, w0.z, acc.z); acc.w = fmaf(hv.x, w0.w, acc.w);
        acc.x = fmaf(hv.y, w1.x, acc.x); acc.y = fmaf(hv.y, w1.y, acc.y);
        acc.z = fmaf(hv.y, w1.z, acc.z); acc.w = fmaf(hv.y, w1.w, acc.w);
        acc.x = fmaf(hv.z, w2.x, acc.x); acc.y = fmaf(hv.z, w2.y, acc.y);
        acc.z = fmaf(hv.z, w2.z, acc.z); acc.w = fmaf(hv.z, w2.w, acc.w);
        acc.x = fmaf(hv.w, w3.x, acc.x); acc.y = fmaf(hv.w, w3.y, acc.y);
        acc.z = fmaf(hv.w, w3.z, acc.z); acc.w = fmaf(hv.w, w3.w, acc.w);
    }
    int row = row0 + r;
    ((float4*)A.Wh)[(size_t)row * 16 + c0] = acc;
    float4 a1 = ((const float4*)A.a)[c0];
    float4 a2 = ((const float4*)A.a)[16 + c0];
    float sv = acc.x * a1.x + acc.y * a1.y + acc.z * a1.z + acc.w * a1.w;
    float tv = acc.x * a2.x + acc.y * a2.y + acc.z * a2.z + acc.w * a2.w;
    #pragma unroll
    for (int off = 8; off; off >>= 1) {        // reduce over 16-lane row group
        sv += __shfl_xor(sv, off, 64);
        tv += __shfl_xor(tv, off, 64);
    }
    if (c0 == 0) { A.s[row] = sv; A.t[row] = tv; }
    float tmax = tv;                           // every lane has its row's tv
    tmax = fmaxf(tmax, __shfl_xor(tmax, 16, 64));
    tmax = fmaxf(tmax, __shfl_xor(tmax, 32, 64));
    if (lane == 0) wmax[wave] = tmax;
    __syncthreads();
    if (tid == 0)
        A.tblkmax[blk] = fmaxf(fmaxf(wmax[0], wmax[1]), fmaxf(wmax[2], wmax[3]));
}

// ---------- K2: LDS hist(+pre merged) + scan + T + packed-key scatter -------
// Round-11 tweak: single pass computes BOTH the full histogram and the
// pre-histogram (predicated) — halves the global loads and t_bin work in
// k2's dominant phase; atomic count unchanged.
__global__ __launch_bounds__(1024) void k2_sort(Args A) {
    __shared__ int hist[NBIN];                  // 32 KB
    __shared__ int pre[NBIN];                   // 32 KB
    __shared__ int wtot[16];
    __shared__ float fmax_[16];
    int tid = threadIdx.x, lane = tid & 63, wave = tid >> 6, blk = blockIdx.x;
    #pragma unroll
    for (int e = tid; e < NBIN; e += 1024) { hist[e] = 0; pre[e] = 0; }
    __syncthreads();
    int my0 = blk * 1024;
    #pragma unroll 4
    for (int e = tid; e < M; e += 1024) {
        float v = (e < N) ? A.t[e] : -A.s[e - N];
        int b = t_bin(v);
        atomicAdd(&hist[b], 1);
        if (e < my0) atomicAdd(&pre[b], 1);
    }
    __syncthreads();
    int b0 = tid * 8;
    int c8[8]; int sum = 0;
    #pragma unroll
    for (int g = 0; g < 8; ++g) { c8[g] = sum; sum += hist[b0 + g]; }
    int inc = sum;
    #pragma unroll
    for (int off = 1; off < 64; off <<= 1) {
        int nb = __shfl_up(inc, off, 64);
        if (lane >= off) inc += nb;
    }
    if (lane == 63) wtot[wave] = inc;
    __syncthreads();
    int wbase = 0;
    #pragma unroll
    for (int w = 0; w < 16; ++w) wbase += (w < wave) ? wtot[w] : 0;
    int tstart = wbase + inc - sum;
    #pragma unroll
    for (int g = 0; g < 8; ++g) {
        int bs = tstart + c8[g];
        hist[b0 + g] = bs;
        pre[b0 + g] += bs;
        A.binstart[b0 + g] = bs;                // benign duplicate across blocks
    }
    if (tid == 0 && blk == 0) A.binstart[NBIN] = M;
    float m = (tid < K1BLKS) ? A.tblkmax[tid] : -3.4e38f;   // 768 k1 blocks
    #pragma unroll
    for (int off = 32; off; off >>= 1) m = fmaxf(m, __shfl_xor(m, off, 64));
    if (lane == 0) fmax_[wave] = m;
    __syncthreads();
    if (tid == 0) {
        float mm = fmax_[0];
        #pragma unroll
        for (int w = 1; w < 16; ++w) mm = fmaxf(mm, fmax_[w]);
        A.Thdr[0] = mm;
    }
    __syncthreads();
    {   // exactly one item per thread (slice == blockDim)
        int e = my0 + tid;
        float v = (e < N) ? A.t[e] : -A.s[e - N];
        int pi = (e < N) ? (e + N) : (e - N);   // queries sort before equal keys
        int pos = atomicAdd(&pre[t_bin(v)], 1);
        A.vals64[pos] = ((unsigned long long)f_ord(v) << 32) | (unsigned)pi;
    }
}

// ---------- K3: exact in-bin rank, 4 THREADS per position ----------
__global__ __launch_bounds__(256) void k3_rank(Args A) {
    __shared__ int parts[256];
    int tid = threadIdx.x;
    int li = tid & 63, sub = tid >> 6;
    int p = blockIdx.x * 64 + li;
    unsigned long long kp = A.vals64[p];
    int b = (int)(kp >> (32 + BSHIFT));
    int lo = A.binstart[b], hi = A.binstart[b + 1];
    int len = hi - lo;
    int qlen = (len + 3) >> 2;
    int qlo = lo + sub * qlen;
    if (qlo > hi) qlo = hi;
    int qhi = qlo + qlen;
    if (qhi > hi) qhi = hi;
    int cnt = 0;
    int q = qlo;
    while (q < qhi && (q & 3)) cnt += (int)(A.vals64[q++] < kp);
    int bend = q + ((qhi - q) & ~3);
    #pragma unroll 2
    for (; q < bend; q += 4) {
        ulonglong2 u0 = *(const ulonglong2*)&A.vals64[q];
        ulonglong2 u1 = *(const ulonglong2*)&A.vals64[q + 2];
        cnt += (int)(u0.x < kp) + (int)(u0.y < kp)
             + (int)(u1.x < kp) + (int)(u1.y < kp);
    }
    while (q < qhi) cnt += (int)(A.vals64[q++] < kp);
    parts[sub * 64 + li] = cnt;
    __syncthreads();
    if (sub == 0) {
        int tot = parts[li] + parts[64 + li] + parts[128 + li] + parts[192 + li];
        int pi = (int)(unsigned)(kp & 0xffffffffu);
        A.tfin[lo + tot] = ord_f((unsigned)(kp >> 32));
        A.idfin[lo + tot] = (pi >= N) ? (pi - N) : (pi + N);
    }
}

// ---------- K4: per-chunk (64 sorted items) key-sums (192 blocks x 128) -----
// Round-11 tweak: 96x256 used only 96 of 256 CUs (Occupancy 3.3% measured on
// k5's twin structure). 192x128 doubles CU coverage -> 2x aggregate
// outstanding-miss capacity for the gather. Algorithm unchanged.
__global__ __launch_bounds__(128) void k4_sums(Args A) {
    int tid = threadIdx.x, wave = tid >> 6, lane = tid & 63;
    int c = blockIdx.x * 2 + wave;              // 384 chunks
    float T = A.Thdr[0];
    float myval = A.tfin[c * 64 + lane];
    int myid = A.idfin[c * 64 + lane];
    float x[64];
    #pragma unroll
    for (int k = 0; k < 64; ++k) {              // 64 independent gathers
        int uid = __shfl(myid, k, 64);
        x[k] = (uid < N) ? A.Wh[(size_t)uid * DOUT + lane] : 0.f;
    }
    float av = 0.f, au = 0.f, svs = 0.f, sus = 0.f;
    #pragma unroll
    for (int k = 0; k < 64; ++k) {
        int uid = __shfl(myid, k, 64);
        if (uid < N) {
            float uval = __shfl(myval, k, 64);
            float wv = expf(0.2f * (uval - T));
            float w2 = wv * wv, w4 = w2 * w2;
            float wu = w4 * wv;                 // exp(uval-T) = wv^5
            av = fmaf(wv, x[k], av); au = fmaf(wu, x[k], au);
            svs += wv; sus += wu;
        }
    }
    A.VU[c * 64 + lane] = make_float2(av, au);
    if (lane == 0) A.sc[c] = make_float2(svs, sus);
}

// ---------- K4b: wave-parallel forward-exclusive scans (65 tasks) ----------
__global__ __launch_bounds__(256) void k4b_scan(Args A) {
    int tid = threadIdx.x, wave = tid >> 6, lane = tid & 63;
    int task = blockIdx.x * 4 + wave;           // 17 blocks -> 68 waves
    if (task >= 65) return;
    const float2* src; float2* dst; int stride, col = 0;
    if (task < 64) { col = task; src = A.VU; dst = A.baseVU; stride = 64; }
    else           { src = A.sc; dst = A.basesc; stride = 1; }
    float bv = 0.f, bu = 0.f;
    for (int c0 = 0; c0 < NCHUNK; c0 += 64) {
        float2 xv = src[(c0 + lane) * stride + col];
        float iv = xv.x, iu = xv.y;
        #pragma unroll
        for (int off = 1; off < 64; off <<= 1) {
            float nv = __shfl_up(iv, off, 64);
            float nu = __shfl_up(iu, off, 64);
            if (lane >= off) { iv += nv; iu += nu; }
        }
        dst[(c0 + lane) * stride + col] = make_float2(bv + iv - xv.x, bu + iu - xv.y);
        bv += __shfl(iv, 63, 64);
        bu += __shfl(iu, 63, 64);
    }
    if (lane == 0) {
        if (task < 64) A.utot[task] = bu;       // U column total
        else           A.utots[0] = bu;         // U scalar total
    }
}

// ---------- K5: sweep with precomputed bases (192 blocks x 128) -------------
__global__ __launch_bounds__(128) void k5_apply(Args A) {
    int tid = threadIdx.x, wave = tid >> 6, lane = tid & 63;
    int c = blockIdx.x * 2 + wave;              // 384 chunks
    float T = A.Thdr[0];
    float myval = A.tfin[c * 64 + lane];
    int myid = A.idfin[c * 64 + lane];
    float x[64];
    #pragma unroll
    for (int k = 0; k < 64; ++k) {              // 64 independent gathers
        int uid = __shfl(myid, k, 64);
        x[k] = (uid < N) ? A.Wh[(size_t)uid * DOUT + lane] : 0.f;
    }
    float2 bvu = A.baseVU[c * 64 + lane];
    float2 bsc = A.basesc[c];
    float rv = bvu.x, ru = bvu.y, rvs = bsc.x, rus = bsc.y;
    float tu  = A.utot[lane];
    float tus = A.utots[0];
    #pragma unroll
    for (int k = 0; k < 64; ++k) {
        float uval = __shfl(myval, k, 64);
        int uid = __shfl(myid, k, 64);
        if (uid < N) {                          // key: advance running sums
            float wv = expf(0.2f * (uval - T));
            float w2 = wv * wv, w4 = w2 * w2;
            float wu = w4 * wv;                 // exp(uval-T)
            rv = fmaf(wv, x[k], rv); ru = fmaf(wu, x[k], ru);
            rvs += wv; rus += wu;
        } else {                                // query: emit output row
            int i = uid - N;
            float si = -uval;
            float xx = si + T;
            float mm = fmaxf(xx, 0.2f * xx);
            float cp_ = expf(xx - mm);
            float cn_ = expf(0.2f * xx - mm);
            float num = cn_ * rv + cp_ * (tu - ru);
            float den = cn_ * rvs + cp_ * (tus - rus);
            float r = num / den;
            A.out[(size_t)i * DOUT + lane] = r > 0.f ? r : expm1f(r);
        }
    }
}

extern "C" void kernel_launch(void* const* d_in, const int* in_sizes, int n_in,
                              void* d_out, int out_size, void* d_ws, size_t ws_size,
                              hipStream_t stream) {
    float* ws = (float*)d_ws;
    size_t o = 0;
    Args A;
    A.h = (const float*)d_in[0];
    A.W = (const float*)d_in[1];
    A.a = (const float*)d_in[2];
    A.out = (float*)d_out;
    A.Wh      = ws + o; o += (size_t)N * DOUT;
    A.s       = ws + o; o += N;
    A.t       = ws + o; o += N;
    A.tblkmax = ws + o; o += K1BLKS;            // 768 k1 blocks
    A.Thdr    = ws + o; o += 16;                // keeps o 16B-aligned
    A.vals64  = (unsigned long long*)(ws + o); o += 2 * (size_t)M;
    A.tfin    = ws + o; o += M;
    A.VU      = (float2*)(ws + o); o += 2 * (size_t)NCHUNK * DOUT;
    A.sc      = (float2*)(ws + o); o += 2 * NCHUNK;
    A.baseVU  = (float2*)(ws + o); o += 2 * (size_t)NCHUNK * DOUT;
    A.basesc  = (float2*)(ws + o); o += 2 * NCHUNK;
    A.utot    = ws + o; o += DOUT;
    A.utots   = ws + o; o += 16;
    A.idfin    = (int*)(ws + o); o += M;
    A.binstart = (int*)(ws + o); o += NBIN + 16;
    // ~4.1 MB total; no initialization required

    k1_gemm <<<K1BLKS, 256, 0, stream>>>(A);
    k2_sort <<<24, 1024, 0, stream>>>(A);
    k3_rank <<<M / 64, 256, 0, stream>>>(A);
    k4_sums <<<NCHUNK / 2, 128, 0, stream>>>(A);
    k4b_scan<<<17, 256, 0, stream>>>(A);
    k5_apply<<<NCHUNK / 2, 128, 0, stream>>>(A);
}

// Round 12
// 124.004 us; speedup vs baseline: 1.1411x; 1.0011x over previous
//
#include <hip/hip_runtime.h>

#define N 12288
#define M (2 * N)          // keys (t_j) + queries (-s_i)
#define DIN 128
#define DOUT 64
#define NBIN 8192
#define BSHIFT 19          // 32 - log2(NBIN)
#define NCHUNK 384         // M / 64
#define K1BLKS 768         // N / 16

// monotone float -> ordered u32 (order-preserving bit transform)
__device__ __forceinline__ unsigned f_ord(float x) {
    unsigned b = __float_as_uint(x);
    return (b & 0x80000000u) ? ~b : (b | 0x80000000u);
}
__device__ __forceinline__ float ord_f(unsigned u) {
    unsigned b = (u & 0x80000000u) ? (u & 0x7FFFFFFFu) : ~u;
    return __uint_as_float(b);
}
__device__ __forceinline__ int t_bin(float x) { return (int)(f_ord(x) >> BSHIFT); }

struct Args {
    const float *h, *W, *a;
    float *Wh, *s, *t, *tblkmax, *Thdr;
    unsigned long long *vals64;     // (ordered(val)<<32)|pi — unique total order
    float *tfin;
    int *idfin, *binstart;
    float2 *VU, *sc;                // per-chunk column/scalar sums {v,u}
    float2 *baseVU, *basesc;        // forward-exclusive prefixes
    float *utot, *utots;            // U totals (suffix = total - prefix)
    float *out;
};

// ---------- K1: Wh = h@W, s, t, per-block max(t) (768 blocks x 256) ---------
// 1 row x 4 cols per thread -> 3072 waves (3/SIMD, 12/CU); LDS 41 KB/block;
// h-tile stride padded 32->33 float4. Proven in round 9 (132.9 -> 127.1).
__global__ __launch_bounds__(256) void k1_gemm(Args A) {
    __shared__ float4 sm4[2576];               // 41 KB: W 2048 + h 16x33
    __shared__ float wmax[4];
    int tid = threadIdx.x, lane = tid & 63, wave = tid >> 6, blk = blockIdx.x;
    float4* Ws4 = sm4;                         // W[k][c4]  (2048)
    float4* hs4 = sm4 + 2048;                  // h[r][k4]  stride 33
    const float4* W4 = (const float4*)A.W;
    #pragma unroll
    for (int e = tid; e < 2048; e += 256) Ws4[e] = W4[e];
    int row0 = blk * 16;
    const float4* h4 = (const float4*)(A.h + (size_t)row0 * DIN);
    #pragma unroll
    for (int e = tid; e < 512; e += 256) hs4[(e >> 5) * 33 + (e & 31)] = h4[e];
    __syncthreads();
    int c0 = tid & 15, r = tid >> 4;           // 16 rows x 16 col-groups
    float4 acc = make_float4(0.f, 0.f, 0.f, 0.f);
    #pragma unroll 4
    for (int kk = 0; kk < 32; ++kk) {
        float4 hv = hs4[r * 33 + kk];          // broadcast among 16 lanes
        float4 w0 = Ws4[(4 * kk + 0) * 16 + c0];
        float4 w1 = Ws4[(4 * kk + 1) * 16 + c0];
        float4 w2 = Ws4[(4 * kk + 2) * 16 + c0];
        float4 w3 = Ws4[(4 * kk + 3) * 16 + c0];
        acc.x = fmaf(hv.x, w0.x, acc.x); acc.y = fmaf(hv.x, w0.y, acc.y);
        acc.z = fmaf(hv.x, w0.z, acc.z); acc.w = fmaf(hv.x, w0.w, acc.w);
        acc.x = fmaf(hv.y, w1.x, acc.x); acc.y = fmaf(hv.y, w1.y, acc.y);
        acc.z = fmaf(hv.y, w1.z, acc.z); acc.w = fmaf(hv.y, w1.w, acc.w);
        acc.x = fmaf(hv.z, w2.x, acc.x); acc.y = fmaf(hv.z, w2.y, acc.y);
        acc.z = fmaf(hv.z, w2.z, acc.z); acc.w = fmaf(hv.z, w2.w, acc.w);
        acc.x = fmaf(hv.w, w3.x, acc.x); acc.y = fmaf(hv.w, w3.y, acc.y);
        acc.z = fmaf(hv.w, w3.z, acc.z); acc.w = fmaf(hv.w, w3.w, acc.w);
    }
    int row = row0 + r;
    ((float4*)A.Wh)[(size_t)row * 16 + c0] = acc;
    float4 a1 = ((const float4*)A.a)[c0];
    float4 a2 = ((const float4*)A.a)[16 + c0];
    float sv = acc.x * a1.x + acc.y * a1.y + acc.z * a1.z + acc.w * a1.w;
    float tv = acc.x * a2.x + acc.y * a2.y + acc.z * a2.z + acc.w * a2.w;
    #pragma unroll
    for (int off = 8; off; off >>= 1) {        // reduce over 16-lane row group
        sv += __shfl_xor(sv, off, 64);
        tv += __shfl_xor(tv, off, 64);
    }
    if (c0 == 0) { A.s[row] = sv; A.t[row] = tv; }
    float tmax = tv;                           // every lane has its row's tv
    tmax = fmaxf(tmax, __shfl_xor(tmax, 16, 64));
    tmax = fmaxf(tmax, __shfl_xor(tmax, 32, 64));
    if (lane == 0) wmax[wave] = tmax;
    __syncthreads();
    if (tid == 0)
        A.tblkmax[blk] = fmaxf(fmaxf(wmax[0], wmax[1]), fmaxf(wmax[2], wmax[3]));
}

// ---------- K2: split-hist LDS + merged pre + scan + T + scatter ------------
// Round-12 tweak: hist split into 2 copies by wave parity (even waves ->
// hist0, odd -> hist1; summed in the scan). Halves same-address collision
// depth on the dominant 24.5k-atomic full-M pass. LDS ~98.5 KB (1 block/CU —
// irrelevant, only 24 blocks).
__global__ __launch_bounds__(1024) void k2_sort(Args A) {
    __shared__ int hist0[NBIN];                 // 32 KB
    __shared__ int hist1[NBIN];                 // 32 KB
    __shared__ int pre[NBIN];                   // 32 KB
    __shared__ int wtot[16];
    __shared__ float fmax_[16];
    int tid = threadIdx.x, lane = tid & 63, wave = tid >> 6, blk = blockIdx.x;
    #pragma unroll
    for (int e = tid; e < NBIN; e += 1024) { hist0[e] = 0; hist1[e] = 0; pre[e] = 0; }
    __syncthreads();
    int my0 = blk * 1024;
    int* myhist = (wave & 1) ? hist1 : hist0;
    #pragma unroll 4
    for (int e = tid; e < M; e += 1024) {
        float v = (e < N) ? A.t[e] : -A.s[e - N];
        int b = t_bin(v);
        atomicAdd(&myhist[b], 1);
        if (e < my0) atomicAdd(&pre[b], 1);
    }
    __syncthreads();
    int b0 = tid * 8;
    int c8[8]; int sum = 0;
    #pragma unroll
    for (int g = 0; g < 8; ++g) { c8[g] = sum; sum += hist0[b0 + g] + hist1[b0 + g]; }
    int inc = sum;
    #pragma unroll
    for (int off = 1; off < 64; off <<= 1) {
        int nb = __shfl_up(inc, off, 64);
        if (lane >= off) inc += nb;
    }
    if (lane == 63) wtot[wave] = inc;
    __syncthreads();
    int wbase = 0;
    #pragma unroll
    for (int w = 0; w < 16; ++w) wbase += (w < wave) ? wtot[w] : 0;
    int tstart = wbase + inc - sum;
    #pragma unroll
    for (int g = 0; g < 8; ++g) {
        int bs = tstart + c8[g];
        pre[b0 + g] += bs;
        A.binstart[b0 + g] = bs;                // benign duplicate across blocks
    }
    if (tid == 0 && blk == 0) A.binstart[NBIN] = M;
    float m = (tid < K1BLKS) ? A.tblkmax[tid] : -3.4e38f;   // 768 k1 blocks
    #pragma unroll
    for (int off = 32; off; off >>= 1) m = fmaxf(m, __shfl_xor(m, off, 64));
    if (lane == 0) fmax_[wave] = m;
    __syncthreads();
    if (tid == 0) {
        float mm = fmax_[0];
        #pragma unroll
        for (int w = 1; w < 16; ++w) mm = fmaxf(mm, fmax_[w]);
        A.Thdr[0] = mm;
    }
    __syncthreads();
    {   // exactly one item per thread (slice == blockDim)
        int e = my0 + tid;
        float v = (e < N) ? A.t[e] : -A.s[e - N];
        int pi = (e < N) ? (e + N) : (e - N);   // queries sort before equal keys
        int pos = atomicAdd(&pre[t_bin(v)], 1);
        A.vals64[pos] = ((unsigned long long)f_ord(v) << 32) | (unsigned)pi;
    }
}

// ---------- K3: exact in-bin rank, 4 THREADS per position ----------
__global__ __launch_bounds__(256) void k3_rank(Args A) {
    __shared__ int parts[256];
    int tid = threadIdx.x;
    int li = tid & 63, sub = tid >> 6;
    int p = blockIdx.x * 64 + li;
    unsigned long long kp = A.vals64[p];
    int b = (int)(kp >> (32 + BSHIFT));
    int lo = A.binstart[b], hi = A.binstart[b + 1];
    int len = hi - lo;
    int qlen = (len + 3) >> 2;
    int qlo = lo + sub * qlen;
    if (qlo > hi) qlo = hi;
    int qhi = qlo + qlen;
    if (qhi > hi) qhi = hi;
    int cnt = 0;
    int q = qlo;
    while (q < qhi && (q & 3)) cnt += (int)(A.vals64[q++] < kp);
    int bend = q + ((qhi - q) & ~3);
    #pragma unroll 2
    for (; q < bend; q += 4) {
        ulonglong2 u0 = *(const ulonglong2*)&A.vals64[q];
        ulonglong2 u1 = *(const ulonglong2*)&A.vals64[q + 2];
        cnt += (int)(u0.x < kp) + (int)(u0.y < kp)
             + (int)(u1.x < kp) + (int)(u1.y < kp);
    }
    while (q < qhi) cnt += (int)(A.vals64[q++] < kp);
    parts[sub * 64 + li] = cnt;
    __syncthreads();
    if (sub == 0) {
        int tot = parts[li] + parts[64 + li] + parts[128 + li] + parts[192 + li];
        int pi = (int)(unsigned)(kp & 0xffffffffu);
        A.tfin[lo + tot] = ord_f((unsigned)(kp >> 32));
        A.idfin[lo + tot] = (pi >= N) ? (pi - N) : (pi + N);
    }
}

// ---------- K4: per-chunk (64 sorted items) key-sums (384 blocks x 64) ------
// Round-12 tweak: 384 one-wave blocks cover all 256 CUs (vs 192 at 192x128)
// -> +33% aggregate outstanding-miss capacity for the gather. No sync in
// this kernel, so the round-4 hazard (barrier at 1 wave/SIMD) doesn't apply.
__global__ __launch_bounds__(64) void k4_sums(Args A) {
    int lane = threadIdx.x;
    int c = blockIdx.x;                         // 384 chunks
    float T = A.Thdr[0];
    float myval = A.tfin[c * 64 + lane];
    int myid = A.idfin[c * 64 + lane];
    float x[64];
    #pragma unroll
    for (int k = 0; k < 64; ++k) {              // 64 independent gathers
        int uid = __shfl(myid, k, 64);
        x[k] = (uid < N) ? A.Wh[(size_t)uid * DOUT + lane] : 0.f;
    }
    float av = 0.f, au = 0.f, svs = 0.f, sus = 0.f;
    #pragma unroll
    for (int k = 0; k < 64; ++k) {
        int uid = __shfl(myid, k, 64);
        if (uid < N) {
            float uval = __shfl(myval, k, 64);
            float wv = expf(0.2f * (uval - T));
            float w2 = wv * wv, w4 = w2 * w2;
            float wu = w4 * wv;                 // exp(uval-T) = wv^5
            av = fmaf(wv, x[k], av); au = fmaf(wu, x[k], au);
            svs += wv; sus += wu;
        }
    }
    A.VU[c * 64 + lane] = make_float2(av, au);
    if (lane == 0) A.sc[c] = make_float2(svs, sus);
}

// ---------- K4b: wave-parallel forward-exclusive scans (65 tasks) ----------
__global__ __launch_bounds__(256) void k4b_scan(Args A) {
    int tid = threadIdx.x, wave = tid >> 6, lane = tid & 63;
    int task = blockIdx.x * 4 + wave;           // 17 blocks -> 68 waves
    if (task >= 65) return;
    const float2* src; float2* dst; int stride, col = 0;
    if (task < 64) { col = task; src = A.VU; dst = A.baseVU; stride = 64; }
    else           { src = A.sc; dst = A.basesc; stride = 1; }
    float bv = 0.f, bu = 0.f;
    for (int c0 = 0; c0 < NCHUNK; c0 += 64) {
        float2 xv = src[(c0 + lane) * stride + col];
        float iv = xv.x, iu = xv.y;
        #pragma unroll
        for (int off = 1; off < 64; off <<= 1) {
            float nv = __shfl_up(iv, off, 64);
            float nu = __shfl_up(iu, off, 64);
            if (lane >= off) { iv += nv; iu += nu; }
        }
        dst[(c0 + lane) * stride + col] = make_float2(bv + iv - xv.x, bu + iu - xv.y);
        bv += __shfl(iv, 63, 64);
        bu += __shfl(iu, 63, 64);
    }
    if (lane == 0) {
        if (task < 64) A.utot[task] = bu;       // U column total
        else           A.utots[0] = bu;         // U scalar total
    }
}

// ---------- K5: sweep with precomputed bases (384 blocks x 64) --------------
__global__ __launch_bounds__(64) void k5_apply(Args A) {
    int lane = threadIdx.x;
    int c = blockIdx.x;                         // 384 chunks
    float T = A.Thdr[0];
    float myval = A.tfin[c * 64 + lane];
    int myid = A.idfin[c * 64 + lane];
    float x[64];
    #pragma unroll
    for (int k = 0; k < 64; ++k) {              // 64 independent gathers
        int uid = __shfl(myid, k, 64);
        x[k] = (uid < N) ? A.Wh[(size_t)uid * DOUT + lane] : 0.f;
    }
    float2 bvu = A.baseVU[c * 64 + lane];
    float2 bsc = A.basesc[c];
    float rv = bvu.x, ru = bvu.y, rvs = bsc.x, rus = bsc.y;
    float tu  = A.utot[lane];
    float tus = A.utots[0];
    #pragma unroll
    for (int k = 0; k < 64; ++k) {
        float uval = __shfl(myval, k, 64);
        int uid = __shfl(myid, k, 64);
        if (uid < N) {                          // key: advance running sums
            float wv = expf(0.2f * (uval - T));
            float w2 = wv * wv, w4 = w2 * w2;
            float wu = w4 * wv;                 // exp(uval-T)
            rv = fmaf(wv, x[k], rv); ru = fmaf(wu, x[k], ru);
            rvs += wv; rus += wu;
        } else {                                // query: emit output row
            int i = uid - N;
            float si = -uval;
            float xx = si + T;
            float mm = fmaxf(xx, 0.2f * xx);
            float cp_ = expf(xx - mm);
            float cn_ = expf(0.2f * xx - mm);
            float num = cn_ * rv + cp_ * (tu - ru);
            float den = cn_ * rvs + cp_ * (tus - rus);
            float r = num / den;
            A.out[(size_t)i * DOUT + lane] = r > 0.f ? r : expm1f(r);
        }
    }
}

extern "C" void kernel_launch(void* const* d_in, const int* in_sizes, int n_in,
                              void* d_out, int out_size, void* d_ws, size_t ws_size,
                              hipStream_t stream) {
    float* ws = (float*)d_ws;
    size_t o = 0;
    Args A;
    A.h = (const float*)d_in[0];
    A.W = (const float*)d_in[1];
    A.a = (const float*)d_in[2];
    A.out = (float*)d_out;
    A.Wh      = ws + o; o += (size_t)N * DOUT;
    A.s       = ws + o; o += N;
    A.t       = ws + o; o += N;
    A.tblkmax = ws + o; o += K1BLKS;            // 768 k1 blocks
    A.Thdr    = ws + o; o += 16;                // keeps o 16B-aligned
    A.vals64  = (unsigned long long*)(ws + o); o += 2 * (size_t)M;
    A.tfin    = ws + o; o += M;
    A.VU      = (float2*)(ws + o); o += 2 * (size_t)NCHUNK * DOUT;
    A.sc      = (float2*)(ws + o); o += 2 * NCHUNK;
    A.baseVU  = (float2*)(ws + o); o += 2 * (size_t)NCHUNK * DOUT;
    A.basesc  = (float2*)(ws + o); o += 2 * NCHUNK;
    A.utot    = ws + o; o += DOUT;
    A.utots   = ws + o; o += 16;
    A.idfin    = (int*)(ws + o); o += M;
    A.binstart = (int*)(ws + o); o += NBIN + 16;
    // ~4.1 MB total; no initialization required

    k1_gemm <<<K1BLKS, 256, 0, stream>>>(A);
    k2_sort <<<24, 1024, 0, stream>>>(A);
    k3_rank <<<M / 64, 256, 0, stream>>>(A);
    k4_sums <<<NCHUNK, 64, 0, stream>>>(A);
    k4b_scan<<<17, 256, 0, stream>>>(A);
    k5_apply<<<NCHUNK, 64, 0, stream>>>(A);
}

// Round 14
// 118.674 us; speedup vs baseline: 1.1923x; 1.0449x over previous
//
#include <hip/hip_runtime.h>

#define N 12288
#define M (2 * N)          // keys (t_j) + queries (-s_i)
#define DIN 128
#define DOUT 64
#define NBIN 8192
#define BSHIFT 19          // 32 - log2(NBIN)
#define NCHUNK 384         // M / 64
#define K1BLKS 768         // N / 16

// monotone float -> ordered u32 (order-preserving bit transform)
__device__ __forceinline__ unsigned f_ord(float x) {
    unsigned b = __float_as_uint(x);
    return (b & 0x80000000u) ? ~b : (b | 0x80000000u);
}
__device__ __forceinline__ float ord_f(unsigned u) {
    unsigned b = (u & 0x80000000u) ? (u & 0x7FFFFFFFu) : ~u;
    return __uint_as_float(b);
}
__device__ __forceinline__ int t_bin(float x) { return (int)(f_ord(x) >> BSHIFT); }

struct Args {
    const float *h, *W, *a;
    float *Wh, *s, *t, *tblkmax, *Thdr;
    unsigned long long *vals64;     // (ordered(val)<<32)|pi — unique total order
    float *tfin;
    int *idfin, *binstart;
    float2 *VU, *sc;                // per-chunk column/scalar sums {v,u}
    float2 *baseVU, *basesc;        // forward-exclusive prefixes
    float *utot, *utots;            // U totals (suffix = total - prefix)
    float *out;
};

// ---------- K1: Wh = h@W, s, t, per-block max(t) (768 blocks x 256) ---------
// 1 row x 4 cols per thread -> 3072 waves (3/SIMD, 12/CU); LDS 41 KB/block;
// h-tile stride padded 32->33 float4. Proven in round 9 (132.9 -> 127.1).
__global__ __launch_bounds__(256) void k1_gemm(Args A) {
    __shared__ float4 sm4[2576];               // 41 KB: W 2048 + h 16x33
    __shared__ float wmax[4];
    int tid = threadIdx.x, lane = tid & 63, wave = tid >> 6, blk = blockIdx.x;
    float4* Ws4 = sm4;                         // W[k][c4]  (2048)
    float4* hs4 = sm4 + 2048;                  // h[r][k4]  stride 33
    const float4* W4 = (const float4*)A.W;
    #pragma unroll
    for (int e = tid; e < 2048; e += 256) Ws4[e] = W4[e];
    int row0 = blk * 16;
    const float4* h4 = (const float4*)(A.h + (size_t)row0 * DIN);
    #pragma unroll
    for (int e = tid; e < 512; e += 256) hs4[(e >> 5) * 33 + (e & 31)] = h4[e];
    __syncthreads();
    int c0 = tid & 15, r = tid >> 4;           // 16 rows x 16 col-groups
    float4 acc = make_float4(0.f, 0.f, 0.f, 0.f);
    #pragma unroll 4
    for (int kk = 0; kk < 32; ++kk) {
        float4 hv = hs4[r * 33 + kk];          // broadcast among 16 lanes
        float4 w0 = Ws4[(4 * kk + 0) * 16 + c0];
        float4 w1 = Ws4[(4 * kk + 1) * 16 + c0];
        float4 w2 = Ws4[(4 * kk + 2) * 16 + c0];
        float4 w3 = Ws4[(4 * kk + 3) * 16 + c0];
        acc.x = fmaf(hv.x, w0.x, acc.x); acc.y = fmaf(hv.x, w0.y, acc.y);
        acc.z = fmaf(hv.x, w0.z, acc.z); acc.w = fmaf(hv.x, w0.w, acc.w);
        acc.x = fmaf(hv.y, w1.x, acc.x); acc.y = fmaf(hv.y, w1.y, acc.y);
        acc.z = fmaf(hv.y, w1.z, acc.z); acc.w = fmaf(hv.y, w1.w, acc.w);
        acc.x = fmaf(hv.z, w2.x, acc.x); acc.y = fmaf(hv.z, w2.y, acc.y);
        acc.z = fmaf(hv.z, w2.z, acc.z); acc.w = fmaf(hv.z, w2.w, acc.w);
        acc.x = fmaf(hv.w, w3.x, acc.x); acc.y = fmaf(hv.w, w3.y, acc.y);
        acc.z = fmaf(hv.w, w3.z, acc.z); acc.w = fmaf(hv.w, w3.w, acc.w);
    }
    int row = row0 + r;
    ((float4*)A.Wh)[(size_t)row * 16 + c0] = acc;
    float4 a1 = ((const float4*)A.a)[c0];
    float4 a2 = ((const float4*)A.a)[16 + c0];
    float sv = acc.x * a1.x + acc.y * a1.y + acc.z * a1.z + acc.w * a1.w;
    float tv = acc.x * a2.x + acc.y * a2.y + acc.z * a2.z + acc.w * a2.w;
    #pragma unroll
    for (int off = 8; off; off >>= 1) {        // reduce over 16-lane row group
        sv += __shfl_xor(sv, off, 64);
        tv += __shfl_xor(tv, off, 64);
    }
    if (c0 == 0) { A.s[row] = sv; A.t[row] = tv; }
    float tmax = tv;                           // every lane has its row's tv
    tmax = fmaxf(tmax, __shfl_xor(tmax, 16, 64));
    tmax = fmaxf(tmax, __shfl_xor(tmax, 32, 64));
    if (lane == 0) wmax[wave] = tmax;
    __syncthreads();
    if (tid == 0)
        A.tblkmax[blk] = fmaxf(fmaxf(wmax[0], wmax[1]), fmaxf(wmax[2], wmax[3]));
}

// ---------- K2: split-hist LDS + merged pre + scan + T + scatter ------------
__global__ __launch_bounds__(1024) void k2_sort(Args A) {
    __shared__ int hist0[NBIN];                 // 32 KB
    __shared__ int hist1[NBIN];                 // 32 KB
    __shared__ int pre[NBIN];                   // 32 KB
    __shared__ int wtot[16];
    __shared__ float fmax_[16];
    int tid = threadIdx.x, lane = tid & 63, wave = tid >> 6, blk = blockIdx.x;
    #pragma unroll
    for (int e = tid; e < NBIN; e += 1024) { hist0[e] = 0; hist1[e] = 0; pre[e] = 0; }
    __syncthreads();
    int my0 = blk * 1024;
    int* myhist = (wave & 1) ? hist1 : hist0;
    #pragma unroll 4
    for (int e = tid; e < M; e += 1024) {
        float v = (e < N) ? A.t[e] : -A.s[e - N];
        int b = t_bin(v);
        atomicAdd(&myhist[b], 1);
        if (e < my0) atomicAdd(&pre[b], 1);
    }
    __syncthreads();
    int b0 = tid * 8;
    int c8[8]; int sum = 0;
    #pragma unroll
    for (int g = 0; g < 8; ++g) { c8[g] = sum; sum += hist0[b0 + g] + hist1[b0 + g]; }
    int inc = sum;
    #pragma unroll
    for (int off = 1; off < 64; off <<= 1) {
        int nb = __shfl_up(inc, off, 64);
        if (lane >= off) inc += nb;
    }
    if (lane == 63) wtot[wave] = inc;
    __syncthreads();
    int wbase = 0;
    #pragma unroll
    for (int w = 0; w < 16; ++w) wbase += (w < wave) ? wtot[w] : 0;
    int tstart = wbase + inc - sum;
    #pragma unroll
    for (int g = 0; g < 8; ++g) {
        int bs = tstart + c8[g];
        pre[b0 + g] += bs;
        A.binstart[b0 + g] = bs;                // benign duplicate across blocks
    }
    if (tid == 0 && blk == 0) A.binstart[NBIN] = M;
    float m = (tid < K1BLKS) ? A.tblkmax[tid] : -3.4e38f;   // 768 k1 blocks
    #pragma unroll
    for (int off = 32; off; off >>= 1) m = fmaxf(m, __shfl_xor(m, off, 64));
    if (lane == 0) fmax_[wave] = m;
    __syncthreads();
    if (tid == 0) {
        float mm = fmax_[0];
        #pragma unroll
        for (int w = 1; w < 16; ++w) mm = fmaxf(mm, fmax_[w]);
        A.Thdr[0] = mm;
    }
    __syncthreads();
    {   // exactly one item per thread (slice == blockDim)
        int e = my0 + tid;
        float v = (e < N) ? A.t[e] : -A.s[e - N];
        int pi = (e < N) ? (e + N) : (e - N);   // queries sort before equal keys
        int pos = atomicAdd(&pre[t_bin(v)], 1);
        A.vals64[pos] = ((unsigned long long)f_ord(v) << 32) | (unsigned)pi;
    }
}

// ---------- K3: exact in-bin rank, 4 THREADS per position ----------
__global__ __launch_bounds__(256) void k3_rank(Args A) {
    __shared__ int parts[256];
    int tid = threadIdx.x;
    int li = tid & 63, sub = tid >> 6;
    int p = blockIdx.x * 64 + li;
    unsigned long long kp = A.vals64[p];
    int b = (int)(kp >> (32 + BSHIFT));
    int lo = A.binstart[b], hi = A.binstart[b + 1];
    int len = hi - lo;
    int qlen = (len + 3) >> 2;
    int qlo = lo + sub * qlen;
    if (qlo > hi) qlo = hi;
    int qhi = qlo + qlen;
    if (qhi > hi) qhi = hi;
    int cnt = 0;
    int q = qlo;
    while (q < qhi && (q & 3)) cnt += (int)(A.vals64[q++] < kp);
    int bend = q + ((qhi - q) & ~3);
    #pragma unroll 2
    for (; q < bend; q += 4) {
        ulonglong2 u0 = *(const ulonglong2*)&A.vals64[q];
        ulonglong2 u1 = *(const ulonglong2*)&A.vals64[q + 2];
        cnt += (int)(u0.x < kp) + (int)(u0.y < kp)
             + (int)(u1.x < kp) + (int)(u1.y < kp);
    }
    while (q < qhi) cnt += (int)(A.vals64[q++] < kp);
    parts[sub * 64 + li] = cnt;
    __syncthreads();
    if (sub == 0) {
        int tot = parts[li] + parts[64 + li] + parts[128 + li] + parts[192 + li];
        int pi = (int)(unsigned)(kp & 0xffffffffu);
        A.tfin[lo + tot] = ord_f((unsigned)(kp >> 32));
        A.idfin[lo + tot] = (pi >= N) ? (pi - N) : (pi + N);
    }
}

// ---------- K4: per-chunk (64 sorted items) key-sums (384 blocks x 64) ------
// Round-14 tweak: __expf (2 instr: v_mul + v_exp_f32) replaces libm expf
// (~15 instr ocml path) — 64 calls on each wave's serial sweep are
// latency-exposed at this occupancy. Args <= 0, values in (0,1]; ~4-ulp
// relative error vs 7.8e-3 existing absmax slack.
__global__ __launch_bounds__(64) void k4_sums(Args A) {
    int lane = threadIdx.x;
    int c = blockIdx.x;                         // 384 chunks
    float T = A.Thdr[0];
    float myval = A.tfin[c * 64 + lane];
    int myid = A.idfin[c * 64 + lane];
    float x[64];
    #pragma unroll
    for (int k = 0; k < 64; ++k) {              // 64 independent gathers
        int uid = __shfl(myid, k, 64);
        x[k] = (uid < N) ? A.Wh[(size_t)uid * DOUT + lane] : 0.f;
    }
    float av = 0.f, au = 0.f, svs = 0.f, sus = 0.f;
    #pragma unroll
    for (int k = 0; k < 64; ++k) {
        int uid = __shfl(myid, k, 64);
        if (uid < N) {
            float uval = __shfl(myval, k, 64);
            float wv = __expf(0.2f * (uval - T));
            float w2 = wv * wv, w4 = w2 * w2;
            float wu = w4 * wv;                 // exp(uval-T) = wv^5
            av = fmaf(wv, x[k], av); au = fmaf(wu, x[k], au);
            svs += wv; sus += wu;
        }
    }
    A.VU[c * 64 + lane] = make_float2(av, au);
    if (lane == 0) A.sc[c] = make_float2(svs, sus);
}

// ---------- K4b: wave-parallel forward-exclusive scans (65 tasks) ----------
__global__ __launch_bounds__(256) void k4b_scan(Args A) {
    int tid = threadIdx.x, wave = tid >> 6, lane = tid & 63;
    int task = blockIdx.x * 4 + wave;           // 17 blocks -> 68 waves
    if (task >= 65) return;
    const float2* src; float2* dst; int stride, col = 0;
    if (task < 64) { col = task; src = A.VU; dst = A.baseVU; stride = 64; }
    else           { src = A.sc; dst = A.basesc; stride = 1; }
    float bv = 0.f, bu = 0.f;
    for (int c0 = 0; c0 < NCHUNK; c0 += 64) {
        float2 xv = src[(c0 + lane) * stride + col];
        float iv = xv.x, iu = xv.y;
        #pragma unroll
        for (int off = 1; off < 64; off <<= 1) {
            float nv = __shfl_up(iv, off, 64);
            float nu = __shfl_up(iu, off, 64);
            if (lane >= off) { iv += nv; iu += nu; }
        }
        dst[(c0 + lane) * stride + col] = make_float2(bv + iv - xv.x, bu + iu - xv.y);
        bv += __shfl(iv, 63, 64);
        bu += __shfl(iu, 63, 64);
    }
    if (lane == 0) {
        if (task < 64) A.utot[task] = bu;       // U column total
        else           A.utots[0] = bu;         // U scalar total
    }
}

// ---------- K5: sweep with precomputed bases (384 blocks x 64) --------------
__global__ __launch_bounds__(64) void k5_apply(Args A) {
    int lane = threadIdx.x;
    int c = blockIdx.x;                         // 384 chunks
    float T = A.Thdr[0];
    float myval = A.tfin[c * 64 + lane];
    int myid = A.idfin[c * 64 + lane];
    float x[64];
    #pragma unroll
    for (int k = 0; k < 64; ++k) {              // 64 independent gathers
        int uid = __shfl(myid, k, 64);
        x[k] = (uid < N) ? A.Wh[(size_t)uid * DOUT + lane] : 0.f;
    }
    float2 bvu = A.baseVU[c * 64 + lane];
    float2 bsc = A.basesc[c];
    float rv = bvu.x, ru = bvu.y, rvs = bsc.x, rus = bsc.y;
    float tu  = A.utot[lane];
    float tus = A.utots[0];
    #pragma unroll
    for (int k = 0; k < 64; ++k) {
        float uval = __shfl(myval, k, 64);
        int uid = __shfl(myid, k, 64);
        if (uid < N) {                          // key: advance running sums
            float wv = __expf(0.2f * (uval - T));
            float w2 = wv * wv, w4 = w2 * w2;
            float wu = w4 * wv;                 // exp(uval-T)
            rv = fmaf(wv, x[k], rv); ru = fmaf(wu, x[k], ru);
            rvs += wv; rus += wu;
        } else {                                // query: emit output row
            int i = uid - N;
            float si = -uval;
            float xx = si + T;
            float mm = fmaxf(xx, 0.2f * xx);
            float cp_ = __expf(xx - mm);
            float cn_ = __expf(0.2f * xx - mm);
            float num = cn_ * rv + cp_ * (tu - ru);
            float den = cn_ * rvs + cp_ * (tus - rus);
            float r = num / den;
            A.out[(size_t)i * DOUT + lane] = r > 0.f ? r : expm1f(r);
        }
    }
}

extern "C" void kernel_launch(void* const* d_in, const int* in_sizes, int n_in,
                              void* d_out, int out_size, void* d_ws, size_t ws_size,
                              hipStream_t stream) {
    float* ws = (float*)d_ws;
    size_t o = 0;
    Args A;
    A.h = (const float*)d_in[0];
    A.W = (const float*)d_in[1];
    A.a = (const float*)d_in[2];
    A.out = (float*)d_out;
    A.Wh      = ws + o; o += (size_t)N * DOUT;
    A.s       = ws + o; o += N;
    A.t       = ws + o; o += N;
    A.tblkmax = ws + o; o += K1BLKS;            // 768 k1 blocks
    A.Thdr    = ws + o; o += 16;                // keeps o 16B-aligned
    A.vals64  = (unsigned long long*)(ws + o); o += 2 * (size_t)M;
    A.tfin    = ws + o; o += M;
    A.VU      = (float2*)(ws + o); o += 2 * (size_t)NCHUNK * DOUT;
    A.sc      = (float2*)(ws + o); o += 2 * NCHUNK;
    A.baseVU  = (float2*)(ws + o); o += 2 * (size_t)NCHUNK * DOUT;
    A.basesc  = (float2*)(ws + o); o += 2 * NCHUNK;
    A.utot    = ws + o; o += DOUT;
    A.utots   = ws + o; o += 16;
    A.idfin    = (int*)(ws + o); o += M;
    A.binstart = (int*)(ws + o); o += NBIN + 16;
    // ~4.1 MB total; no initialization required

    k1_gemm <<<K1BLKS, 256, 0, stream>>>(A);
    k2_sort <<<24, 1024, 0, stream>>>(A);
    k3_rank <<<M / 64, 256, 0, stream>>>(A);
    k4_sums <<<NCHUNK, 64, 0, stream>>>(A);
    k4b_scan<<<17, 256, 0, stream>>>(A);
    k5_apply<<<NCHUNK, 64, 0, stream>>>(A);
}

// Round 15
// 111.979 us; speedup vs baseline: 1.2636x; 1.0598x over previous
//
#include <hip/hip_runtime.h>

#define N 12288
#define M (2 * N)          // keys (t_j) + queries (-s_i)
#define DIN 128
#define DOUT 64
#define NBIN 8192
#define BSHIFT 19          // 32 - log2(NBIN)
#define NCHUNK 384         // M / 64
#define K1BLKS 768         // N / 16

// monotone float -> ordered u32 (order-preserving bit transform)
__device__ __forceinline__ unsigned f_ord(float x) {
    unsigned b = __float_as_uint(x);
    return (b & 0x80000000u) ? ~b : (b | 0x80000000u);
}
__device__ __forceinline__ float ord_f(unsigned u) {
    unsigned b = (u & 0x80000000u) ? (u & 0x7FFFFFFFu) : ~u;
    return __uint_as_float(b);
}
__device__ __forceinline__ int t_bin(float x) { return (int)(f_ord(x) >> BSHIFT); }

struct Args {
    const float *h, *W, *a;
    float *Wh, *s, *t, *tblkmax, *Thdr;
    unsigned long long *vals64;     // (ordered(val)<<32)|pi — unique total order
    float *tfin;
    int *idfin, *binstart;
    float2 *VU, *sc;                // per-chunk column/scalar sums {v,u}
    float2 *baseVU, *basesc;        // forward-exclusive prefixes
    float *utot, *utots;            // U totals (suffix = total - prefix)
    float *out;
};

// ---------- K1: Wh = h@W, s, t, per-block max(t) (768 blocks x 256) ---------
// 1 row x 4 cols per thread -> 3072 waves (3/SIMD, 12/CU); LDS 41 KB/block;
// h-tile stride padded 32->33 float4. Proven in round 9 (132.9 -> 127.1).
__global__ __launch_bounds__(256) void k1_gemm(Args A) {
    __shared__ float4 sm4[2576];               // 41 KB: W 2048 + h 16x33
    __shared__ float wmax[4];
    int tid = threadIdx.x, lane = tid & 63, wave = tid >> 6, blk = blockIdx.x;
    float4* Ws4 = sm4;                         // W[k][c4]  (2048)
    float4* hs4 = sm4 + 2048;                  // h[r][k4]  stride 33
    const float4* W4 = (const float4*)A.W;
    #pragma unroll
    for (int e = tid; e < 2048; e += 256) Ws4[e] = W4[e];
    int row0 = blk * 16;
    const float4* h4 = (const float4*)(A.h + (size_t)row0 * DIN);
    #pragma unroll
    for (int e = tid; e < 512; e += 256) hs4[(e >> 5) * 33 + (e & 31)] = h4[e];
    __syncthreads();
    int c0 = tid & 15, r = tid >> 4;           // 16 rows x 16 col-groups
    float4 acc = make_float4(0.f, 0.f, 0.f, 0.f);
    #pragma unroll 4
    for (int kk = 0; kk < 32; ++kk) {
        float4 hv = hs4[r * 33 + kk];          // broadcast among 16 lanes
        float4 w0 = Ws4[(4 * kk + 0) * 16 + c0];
        float4 w1 = Ws4[(4 * kk + 1) * 16 + c0];
        float4 w2 = Ws4[(4 * kk + 2) * 16 + c0];
        float4 w3 = Ws4[(4 * kk + 3) * 16 + c0];
        acc.x = fmaf(hv.x, w0.x, acc.x); acc.y = fmaf(hv.x, w0.y, acc.y);
        acc.z = fmaf(hv.x, w0.z, acc.z); acc.w = fmaf(hv.x, w0.w, acc.w);
        acc.x = fmaf(hv.y, w1.x, acc.x); acc.y = fmaf(hv.y, w1.y, acc.y);
        acc.z = fmaf(hv.y, w1.z, acc.z); acc.w = fmaf(hv.y, w1.w, acc.w);
        acc.x = fmaf(hv.z, w2.x, acc.x); acc.y = fmaf(hv.z, w2.y, acc.y);
        acc.z = fmaf(hv.z, w2.z, acc.z); acc.w = fmaf(hv.z, w2.w, acc.w);
        acc.x = fmaf(hv.w, w3.x, acc.x); acc.y = fmaf(hv.w, w3.y, acc.y);
        acc.z = fmaf(hv.w, w3.z, acc.z); acc.w = fmaf(hv.w, w3.w, acc.w);
    }
    int row = row0 + r;
    ((float4*)A.Wh)[(size_t)row * 16 + c0] = acc;
    float4 a1 = ((const float4*)A.a)[c0];
    float4 a2 = ((const float4*)A.a)[16 + c0];
    float sv = acc.x * a1.x + acc.y * a1.y + acc.z * a1.z + acc.w * a1.w;
    float tv = acc.x * a2.x + acc.y * a2.y + acc.z * a2.z + acc.w * a2.w;
    #pragma unroll
    for (int off = 8; off; off >>= 1) {        // reduce over 16-lane row group
        sv += __shfl_xor(sv, off, 64);
        tv += __shfl_xor(tv, off, 64);
    }
    if (c0 == 0) { A.s[row] = sv; A.t[row] = tv; }
    float tmax = tv;                           // every lane has its row's tv
    tmax = fmaxf(tmax, __shfl_xor(tmax, 16, 64));
    tmax = fmaxf(tmax, __shfl_xor(tmax, 32, 64));
    if (lane == 0) wmax[wave] = tmax;
    __syncthreads();
    if (tid == 0)
        A.tblkmax[blk] = fmaxf(fmaxf(wmax[0], wmax[1]), fmaxf(wmax[2], wmax[3]));
}

// ---------- K2: split-hist LDS + merged pre + scan + T + scatter ------------
__global__ __launch_bounds__(1024) void k2_sort(Args A) {
    __shared__ int hist0[NBIN];                 // 32 KB
    __shared__ int hist1[NBIN];                 // 32 KB
    __shared__ int pre[NBIN];                   // 32 KB
    __shared__ int wtot[16];
    __shared__ float fmax_[16];
    int tid = threadIdx.x, lane = tid & 63, wave = tid >> 6, blk = blockIdx.x;
    #pragma unroll
    for (int e = tid; e < NBIN; e += 1024) { hist0[e] = 0; hist1[e] = 0; pre[e] = 0; }
    __syncthreads();
    int my0 = blk * 1024;
    int* myhist = (wave & 1) ? hist1 : hist0;
    #pragma unroll 4
    for (int e = tid; e < M; e += 1024) {
        float v = (e < N) ? A.t[e] : -A.s[e - N];
        int b = t_bin(v);
        atomicAdd(&myhist[b], 1);
        if (e < my0) atomicAdd(&pre[b], 1);
    }
    __syncthreads();
    int b0 = tid * 8;
    int c8[8]; int sum = 0;
    #pragma unroll
    for (int g = 0; g < 8; ++g) { c8[g] = sum; sum += hist0[b0 + g] + hist1[b0 + g]; }
    int inc = sum;
    #pragma unroll
    for (int off = 1; off < 64; off <<= 1) {
        int nb = __shfl_up(inc, off, 64);
        if (lane >= off) inc += nb;
    }
    if (lane == 63) wtot[wave] = inc;
    __syncthreads();
    int wbase = 0;
    #pragma unroll
    for (int w = 0; w < 16; ++w) wbase += (w < wave) ? wtot[w] : 0;
    int tstart = wbase + inc - sum;
    #pragma unroll
    for (int g = 0; g < 8; ++g) {
        int bs = tstart + c8[g];
        pre[b0 + g] += bs;
        A.binstart[b0 + g] = bs;                // benign duplicate across blocks
    }
    if (tid == 0 && blk == 0) A.binstart[NBIN] = M;
    float m = (tid < K1BLKS) ? A.tblkmax[tid] : -3.4e38f;   // 768 k1 blocks
    #pragma unroll
    for (int off = 32; off; off >>= 1) m = fmaxf(m, __shfl_xor(m, off, 64));
    if (lane == 0) fmax_[wave] = m;
    __syncthreads();
    if (tid == 0) {
        float mm = fmax_[0];
        #pragma unroll
        for (int w = 1; w < 16; ++w) mm = fmaxf(mm, fmax_[w]);
        A.Thdr[0] = mm;
    }
    __syncthreads();
    {   // exactly one item per thread (slice == blockDim)
        int e = my0 + tid;
        float v = (e < N) ? A.t[e] : -A.s[e - N];
        int pi = (e < N) ? (e + N) : (e - N);   // queries sort before equal keys
        int pos = atomicAdd(&pre[t_bin(v)], 1);
        A.vals64[pos] = ((unsigned long long)f_ord(v) << 32) | (unsigned)pi;
    }
}

// ---------- K3: exact in-bin rank, 4 THREADS per position ----------
__global__ __launch_bounds__(256) void k3_rank(Args A) {
    __shared__ int parts[256];
    int tid = threadIdx.x;
    int li = tid & 63, sub = tid >> 6;
    int p = blockIdx.x * 64 + li;
    unsigned long long kp = A.vals64[p];
    int b = (int)(kp >> (32 + BSHIFT));
    int lo = A.binstart[b], hi = A.binstart[b + 1];
    int len = hi - lo;
    int qlen = (len + 3) >> 2;
    int qlo = lo + sub * qlen;
    if (qlo > hi) qlo = hi;
    int qhi = qlo + qlen;
    if (qhi > hi) qhi = hi;
    int cnt = 0;
    int q = qlo;
    while (q < qhi && (q & 3)) cnt += (int)(A.vals64[q++] < kp);
    int bend = q + ((qhi - q) & ~3);
    #pragma unroll 2
    for (; q < bend; q += 4) {
        ulonglong2 u0 = *(const ulonglong2*)&A.vals64[q];
        ulonglong2 u1 = *(const ulonglong2*)&A.vals64[q + 2];
        cnt += (int)(u0.x < kp) + (int)(u0.y < kp)
             + (int)(u1.x < kp) + (int)(u1.y < kp);
    }
    while (q < qhi) cnt += (int)(A.vals64[q++] < kp);
    parts[sub * 64 + li] = cnt;
    __syncthreads();
    if (sub == 0) {
        int tot = parts[li] + parts[64 + li] + parts[128 + li] + parts[192 + li];
        int pi = (int)(unsigned)(kp & 0xffffffffu);
        A.tfin[lo + tot] = ord_f((unsigned)(kp >> 32));
        A.idfin[lo + tot] = (pi >= N) ? (pi - N) : (pi + N);
    }
}

// ---------- K4: per-chunk (64 sorted items) key-sums (384 blocks x 64) ------
// Round-15: exp hoisted OUT of the sweep — each lane computes its own
// wvm/wum once in parallel (bit-identical to the old per-iteration broadcast
// values), the sweep uses __shfl(wvm,k). __ballot keymask gives the compiler
// a scalar (s_cbranch) loop condition instead of a per-iter vector compare.
__global__ __launch_bounds__(64) void k4_sums(Args A) {
    int lane = threadIdx.x;
    int c = blockIdx.x;                         // 384 chunks
    float T = A.Thdr[0];
    float myval = A.tfin[c * 64 + lane];
    int myid = A.idfin[c * 64 + lane];
    float x[64];
    #pragma unroll
    for (int k = 0; k < 64; ++k) {              // 64 independent gathers
        int uid = __shfl(myid, k, 64);
        x[k] = (uid < N) ? A.Wh[(size_t)uid * DOUT + lane] : 0.f;
    }
    float wvm = 0.f, wum = 0.f;
    if (myid < N) {
        wvm = __expf(0.2f * (myval - T));
        float w2 = wvm * wvm, w4 = w2 * w2;
        wum = w4 * wvm;                         // exp(myval-T) = wvm^5
    }
    unsigned long long keymask = __ballot(myid < N);
    float av = 0.f, au = 0.f, svs = 0.f, sus = 0.f;
    #pragma unroll
    for (int k = 0; k < 64; ++k) {
        if ((keymask >> k) & 1) {
            float wv = __shfl(wvm, k, 64);
            float wu = __shfl(wum, k, 64);
            av = fmaf(wv, x[k], av); au = fmaf(wu, x[k], au);
            svs += wv; sus += wu;
        }
    }
    A.VU[c * 64 + lane] = make_float2(av, au);
    if (lane == 0) A.sc[c] = make_float2(svs, sus);
}

// ---------- K4b: wave-parallel forward-exclusive scans (65 tasks) ----------
__global__ __launch_bounds__(256) void k4b_scan(Args A) {
    int tid = threadIdx.x, wave = tid >> 6, lane = tid & 63;
    int task = blockIdx.x * 4 + wave;           // 17 blocks -> 68 waves
    if (task >= 65) return;
    const float2* src; float2* dst; int stride, col = 0;
    if (task < 64) { col = task; src = A.VU; dst = A.baseVU; stride = 64; }
    else           { src = A.sc; dst = A.basesc; stride = 1; }
    float bv = 0.f, bu = 0.f;
    for (int c0 = 0; c0 < NCHUNK; c0 += 64) {
        float2 xv = src[(c0 + lane) * stride + col];
        float iv = xv.x, iu = xv.y;
        #pragma unroll
        for (int off = 1; off < 64; off <<= 1) {
            float nv = __shfl_up(iv, off, 64);
            float nu = __shfl_up(iu, off, 64);
            if (lane >= off) { iv += nv; iu += nu; }
        }
        dst[(c0 + lane) * stride + col] = make_float2(bv + iv - xv.x, bu + iu - xv.y);
        bv += __shfl(iv, 63, 64);
        bu += __shfl(iu, 63, 64);
    }
    if (lane == 0) {
        if (task < 64) A.utot[task] = bu;       // U column total
        else           A.utots[0] = bu;         // U scalar total
    }
}

// ---------- K5: sweep with precomputed bases (384 blocks x 64) --------------
// Round-15: same exp-hoist + keymask as k4; query path uses __fdividef
// (v_rcp+mul vs IEEE divide seq) and __expf(r)-1 for expm1f (absolute error
// ~1e-7 vs 7.8e-3 tolerance; r <= 0 on that path). myval/myid shfls moved
// inside the (rarer) query branch.
__global__ __launch_bounds__(64) void k5_apply(Args A) {
    int lane = threadIdx.x;
    int c = blockIdx.x;                         // 384 chunks
    float T = A.Thdr[0];
    float myval = A.tfin[c * 64 + lane];
    int myid = A.idfin[c * 64 + lane];
    float x[64];
    #pragma unroll
    for (int k = 0; k < 64; ++k) {              // 64 independent gathers
        int uid = __shfl(myid, k, 64);
        x[k] = (uid < N) ? A.Wh[(size_t)uid * DOUT + lane] : 0.f;
    }
    float wvm = 0.f, wum = 0.f;
    if (myid < N) {
        wvm = __expf(0.2f * (myval - T));
        float w2 = wvm * wvm, w4 = w2 * w2;
        wum = w4 * wvm;                         // exp(myval-T) = wvm^5
    }
    unsigned long long keymask = __ballot(myid < N);
    float2 bvu = A.baseVU[c * 64 + lane];
    float2 bsc = A.basesc[c];
    float rv = bvu.x, ru = bvu.y, rvs = bsc.x, rus = bsc.y;
    float tu  = A.utot[lane];
    float tus = A.utots[0];
    #pragma unroll
    for (int k = 0; k < 64; ++k) {
        if ((keymask >> k) & 1) {               // key: advance running sums
            float wv = __shfl(wvm, k, 64);
            float wu = __shfl(wum, k, 64);
            rv = fmaf(wv, x[k], rv); ru = fmaf(wu, x[k], ru);
            rvs += wv; rus += wu;
        } else {                                // query: emit output row
            float uval = __shfl(myval, k, 64);
            int uid = __shfl(myid, k, 64);
            int i = uid - N;
            float xx = -uval + T;
            float mm = fmaxf(xx, 0.2f * xx);
            float cp_ = __expf(xx - mm);
            float cn_ = __expf(0.2f * xx - mm);
            float num = cn_ * rv + cp_ * (tu - ru);
            float den = cn_ * rvs + cp_ * (tus - rus);
            float r = __fdividef(num, den);
            A.out[(size_t)i * DOUT + lane] = r > 0.f ? r : (__expf(r) - 1.f);
        }
    }
}

extern "C" void kernel_launch(void* const* d_in, const int* in_sizes, int n_in,
                              void* d_out, int out_size, void* d_ws, size_t ws_size,
                              hipStream_t stream) {
    float* ws = (float*)d_ws;
    size_t o = 0;
    Args A;
    A.h = (const float*)d_in[0];
    A.W = (const float*)d_in[1];
    A.a = (const float*)d_in[2];
    A.out = (float*)d_out;
    A.Wh      = ws + o; o += (size_t)N * DOUT;
    A.s       = ws + o; o += N;
    A.t       = ws + o; o += N;
    A.tblkmax = ws + o; o += K1BLKS;            // 768 k1 blocks
    A.Thdr    = ws + o; o += 16;                // keeps o 16B-aligned
    A.vals64  = (unsigned long long*)(ws + o); o += 2 * (size_t)M;
    A.tfin    = ws + o; o += M;
    A.VU      = (float2*)(ws + o); o += 2 * (size_t)NCHUNK * DOUT;
    A.sc      = (float2*)(ws + o); o += 2 * NCHUNK;
    A.baseVU  = (float2*)(ws + o); o += 2 * (size_t)NCHUNK * DOUT;
    A.basesc  = (float2*)(ws + o); o += 2 * NCHUNK;
    A.utot    = ws + o; o += DOUT;
    A.utots   = ws + o; o += 16;
    A.idfin    = (int*)(ws + o); o += M;
    A.binstart = (int*)(ws + o); o += NBIN + 16;
    // ~4.1 MB total; no initialization required

    k1_gemm <<<K1BLKS, 256, 0, stream>>>(A);
    k2_sort <<<24, 1024, 0, stream>>>(A);
    k3_rank <<<M / 64, 256, 0, stream>>>(A);
    k4_sums <<<NCHUNK, 64, 0, stream>>>(A);
    k4b_scan<<<17, 256, 0, stream>>>(A);
    k5_apply<<<NCHUNK, 64, 0, stream>>>(A);
}

// Round 16
// 105.693 us; speedup vs baseline: 1.3388x; 1.0595x over previous
//
#include <hip/hip_runtime.h>

#define N 12288
#define M (2 * N)          // keys (t_j) + queries (-s_i)
#define DIN 128
#define DOUT 64
#define NBIN 8192
#define BSHIFT 19          // 32 - log2(NBIN)
#define NCHUNK 384         // M / 64
#define K1BLKS 768         // N / 16

// monotone float -> ordered u32 (order-preserving bit transform)
__device__ __forceinline__ unsigned f_ord(float x) {
    unsigned b = __float_as_uint(x);
    return (b & 0x80000000u) ? ~b : (b | 0x80000000u);
}
__device__ __forceinline__ float ord_f(unsigned u) {
    unsigned b = (u & 0x80000000u) ? (u & 0x7FFFFFFFu) : ~u;
    return __uint_as_float(b);
}
__device__ __forceinline__ int t_bin(float x) { return (int)(f_ord(x) >> BSHIFT); }

struct Args {
    const float *h, *W, *a;
    float *Wh, *s, *t, *tblkmax, *Thdr;
    unsigned long long *vals64;     // (ordered(val)<<32)|pi — unique total order
    float *tfin;
    int *idfin, *binstart;
    float2 *VU, *sc;                // per-chunk column/scalar sums {v,u}
    float2 *baseVU, *basesc;        // forward-exclusive prefixes
    float *utot, *utots;            // U totals (suffix = total - prefix)
    float *out;
};

// ---------- K1: Wh = h@W, s, t, per-block max(t) (768 blocks x 256) ---------
// 1 row x 4 cols per thread -> 3072 waves (3/SIMD, 12/CU); LDS 41 KB/block;
// h-tile stride padded 32->33 float4. Proven in round 9 (132.9 -> 127.1).
__global__ __launch_bounds__(256) void k1_gemm(Args A) {
    __shared__ float4 sm4[2576];               // 41 KB: W 2048 + h 16x33
    __shared__ float wmax[4];
    int tid = threadIdx.x, lane = tid & 63, wave = tid >> 6, blk = blockIdx.x;
    float4* Ws4 = sm4;                         // W[k][c4]  (2048)
    float4* hs4 = sm4 + 2048;                  // h[r][k4]  stride 33
    const float4* W4 = (const float4*)A.W;
    #pragma unroll
    for (int e = tid; e < 2048; e += 256) Ws4[e] = W4[e];
    int row0 = blk * 16;
    const float4* h4 = (const float4*)(A.h + (size_t)row0 * DIN);
    #pragma unroll
    for (int e = tid; e < 512; e += 256) hs4[(e >> 5) * 33 + (e & 31)] = h4[e];
    __syncthreads();
    int c0 = tid & 15, r = tid >> 4;           // 16 rows x 16 col-groups
    float4 acc = make_float4(0.f, 0.f, 0.f, 0.f);
    #pragma unroll 4
    for (int kk = 0; kk < 32; ++kk) {
        float4 hv = hs4[r * 33 + kk];          // broadcast among 16 lanes
        float4 w0 = Ws4[(4 * kk + 0) * 16 + c0];
        float4 w1 = Ws4[(4 * kk + 1) * 16 + c0];
        float4 w2 = Ws4[(4 * kk + 2) * 16 + c0];
        float4 w3 = Ws4[(4 * kk + 3) * 16 + c0];
        acc.x = fmaf(hv.x, w0.x, acc.x); acc.y = fmaf(hv.x, w0.y, acc.y);
        acc.z = fmaf(hv.x, w0.z, acc.z); acc.w = fmaf(hv.x, w0.w, acc.w);
        acc.x = fmaf(hv.y, w1.x, acc.x); acc.y = fmaf(hv.y, w1.y, acc.y);
        acc.z = fmaf(hv.y, w1.z, acc.z); acc.w = fmaf(hv.y, w1.w, acc.w);
        acc.x = fmaf(hv.z, w2.x, acc.x); acc.y = fmaf(hv.z, w2.y, acc.y);
        acc.z = fmaf(hv.z, w2.z, acc.z); acc.w = fmaf(hv.z, w2.w, acc.w);
        acc.x = fmaf(hv.w, w3.x, acc.x); acc.y = fmaf(hv.w, w3.y, acc.y);
        acc.z = fmaf(hv.w, w3.z, acc.z); acc.w = fmaf(hv.w, w3.w, acc.w);
    }
    int row = row0 + r;
    ((float4*)A.Wh)[(size_t)row * 16 + c0] = acc;
    float4 a1 = ((const float4*)A.a)[c0];
    float4 a2 = ((const float4*)A.a)[16 + c0];
    float sv = acc.x * a1.x + acc.y * a1.y + acc.z * a1.z + acc.w * a1.w;
    float tv = acc.x * a2.x + acc.y * a2.y + acc.z * a2.z + acc.w * a2.w;
    #pragma unroll
    for (int off = 8; off; off >>= 1) {        // reduce over 16-lane row group
        sv += __shfl_xor(sv, off, 64);
        tv += __shfl_xor(tv, off, 64);
    }
    if (c0 == 0) { A.s[row] = sv; A.t[row] = tv; }
    float tmax = tv;                           // every lane has its row's tv
    tmax = fmaxf(tmax, __shfl_xor(tmax, 16, 64));
    tmax = fmaxf(tmax, __shfl_xor(tmax, 32, 64));
    if (lane == 0) wmax[wave] = tmax;
    __syncthreads();
    if (tid == 0)
        A.tblkmax[blk] = fmaxf(fmaxf(wmax[0], wmax[1]), fmaxf(wmax[2], wmax[3]));
}

// ---------- K2: float4 hist pass + split-hist + scan + T + scatter ----------
// Round-16: the dominant full-M pass now reads float4 (6 iters/thread vs 24
// scalar): N = 3*4096 so iters 0-2 are pure-t, 3-5 pure-s. my0 is a multiple
// of 1024 -> the pre-hist predicate holds per-quad. Atomic counts and bin
// math unchanged (exact).
__global__ __launch_bounds__(1024) void k2_sort(Args A) {
    __shared__ int hist0[NBIN];                 // 32 KB
    __shared__ int hist1[NBIN];                 // 32 KB
    __shared__ int pre[NBIN];                   // 32 KB
    __shared__ int wtot[16];
    __shared__ float fmax_[16];
    int tid = threadIdx.x, lane = tid & 63, wave = tid >> 6, blk = blockIdx.x;
    #pragma unroll
    for (int e = tid; e < NBIN; e += 1024) { hist0[e] = 0; hist1[e] = 0; pre[e] = 0; }
    __syncthreads();
    int my0 = blk * 1024;
    int* myhist = (wave & 1) ? hist1 : hist0;
    #pragma unroll
    for (int it = 0; it < 6; ++it) {
        int qi = it * 1024 + tid;               // quad index; covers M/4 quads
        int e4 = qi * 4;                        // first element of the quad
        float4 v4;
        if (it < 3) {
            v4 = ((const float4*)A.t)[qi];
        } else {
            float4 s4 = ((const float4*)A.s)[qi - 3072];
            v4 = make_float4(-s4.x, -s4.y, -s4.z, -s4.w);
        }
        int ba = t_bin(v4.x), bb = t_bin(v4.y), bc = t_bin(v4.z), bd = t_bin(v4.w);
        atomicAdd(&myhist[ba], 1); atomicAdd(&myhist[bb], 1);
        atomicAdd(&myhist[bc], 1); atomicAdd(&myhist[bd], 1);
        if (e4 < my0) {                         // quad fully before my0 (4 | my0)
            atomicAdd(&pre[ba], 1); atomicAdd(&pre[bb], 1);
            atomicAdd(&pre[bc], 1); atomicAdd(&pre[bd], 1);
        }
    }
    __syncthreads();
    int b0 = tid * 8;
    int c8[8]; int sum = 0;
    #pragma unroll
    for (int g = 0; g < 8; ++g) { c8[g] = sum; sum += hist0[b0 + g] + hist1[b0 + g]; }
    int inc = sum;
    #pragma unroll
    for (int off = 1; off < 64; off <<= 1) {
        int nb = __shfl_up(inc, off, 64);
        if (lane >= off) inc += nb;
    }
    if (lane == 63) wtot[wave] = inc;
    __syncthreads();
    int wbase = 0;
    #pragma unroll
    for (int w = 0; w < 16; ++w) wbase += (w < wave) ? wtot[w] : 0;
    int tstart = wbase + inc - sum;
    #pragma unroll
    for (int g = 0; g < 8; ++g) {
        int bs = tstart + c8[g];
        pre[b0 + g] += bs;
        A.binstart[b0 + g] = bs;                // benign duplicate across blocks
    }
    if (tid == 0 && blk == 0) A.binstart[NBIN] = M;
    float m = (tid < K1BLKS) ? A.tblkmax[tid] : -3.4e38f;   // 768 k1 blocks
    #pragma unroll
    for (int off = 32; off; off >>= 1) m = fmaxf(m, __shfl_xor(m, off, 64));
    if (lane == 0) fmax_[wave] = m;
    __syncthreads();
    if (tid == 0) {
        float mm = fmax_[0];
        #pragma unroll
        for (int w = 1; w < 16; ++w) mm = fmaxf(mm, fmax_[w]);
        A.Thdr[0] = mm;
    }
    __syncthreads();
    {   // exactly one item per thread (slice == blockDim)
        int e = my0 + tid;
        float v = (e < N) ? A.t[e] : -A.s[e - N];
        int pi = (e < N) ? (e + N) : (e - N);   // queries sort before equal keys
        int pos = atomicAdd(&pre[t_bin(v)], 1);
        A.vals64[pos] = ((unsigned long long)f_ord(v) << 32) | (unsigned)pi;
    }
}

// ---------- K3: exact in-bin rank, 8 THREADS per position ----------
// Round-16: subs 4 -> 8 (768 blocks x 256, 32 positions/block) halves the
// per-thread scan of the hottest bins (tail sets this kernel's duration).
__global__ __launch_bounds__(256) void k3_rank(Args A) {
    __shared__ int parts[256];
    int tid = threadIdx.x;
    int li = tid & 31, sub = tid >> 5;          // 32 positions x 8 subs
    int p = blockIdx.x * 32 + li;
    unsigned long long kp = A.vals64[p];
    int b = (int)(kp >> (32 + BSHIFT));
    int lo = A.binstart[b], hi = A.binstart[b + 1];
    int len = hi - lo;
    int qlen = (len + 7) >> 3;
    int qlo = lo + sub * qlen;
    if (qlo > hi) qlo = hi;
    int qhi = qlo + qlen;
    if (qhi > hi) qhi = hi;
    int cnt = 0;
    int q = qlo;
    while (q < qhi && (q & 3)) cnt += (int)(A.vals64[q++] < kp);
    int bend = q + ((qhi - q) & ~3);
    #pragma unroll 2
    for (; q < bend; q += 4) {
        ulonglong2 u0 = *(const ulonglong2*)&A.vals64[q];
        ulonglong2 u1 = *(const ulonglong2*)&A.vals64[q + 2];
        cnt += (int)(u0.x < kp) + (int)(u0.y < kp)
             + (int)(u1.x < kp) + (int)(u1.y < kp);
    }
    while (q < qhi) cnt += (int)(A.vals64[q++] < kp);
    parts[sub * 32 + li] = cnt;
    __syncthreads();
    if (sub == 0) {
        int tot = 0;
        #pragma unroll
        for (int s2 = 0; s2 < 8; ++s2) tot += parts[s2 * 32 + li];
        int pi = (int)(unsigned)(kp & 0xffffffffu);
        A.tfin[lo + tot] = ord_f((unsigned)(kp >> 32));
        A.idfin[lo + tot] = (pi >= N) ? (pi - N) : (pi + N);
    }
}

// ---------- K4: per-chunk (64 sorted items) key-sums (384 blocks x 64) ------
// Round-16: branchless sweep — wvm/wum and x[k] are already 0 for query
// lanes, so unconditional fmaf is bit-identical and drops 64 mask tests
// from the serial loop (k4 has no prefix semantics, unlike k5).
__global__ __launch_bounds__(64) void k4_sums(Args A) {
    int lane = threadIdx.x;
    int c = blockIdx.x;                         // 384 chunks
    float T = A.Thdr[0];
    float myval = A.tfin[c * 64 + lane];
    int myid = A.idfin[c * 64 + lane];
    float x[64];
    #pragma unroll
    for (int k = 0; k < 64; ++k) {              // 64 independent gathers
        int uid = __shfl(myid, k, 64);
        x[k] = (uid < N) ? A.Wh[(size_t)uid * DOUT + lane] : 0.f;
    }
    float wvm = 0.f, wum = 0.f;
    if (myid < N) {
        wvm = __expf(0.2f * (myval - T));
        float w2 = wvm * wvm, w4 = w2 * w2;
        wum = w4 * wvm;                         // exp(myval-T) = wvm^5
    }
    float av = 0.f, au = 0.f, svs = 0.f, sus = 0.f;
    #pragma unroll
    for (int k = 0; k < 64; ++k) {
        float wv = __shfl(wvm, k, 64);
        float wu = __shfl(wum, k, 64);
        av = fmaf(wv, x[k], av); au = fmaf(wu, x[k], au);
        svs += wv; sus += wu;
    }
    A.VU[c * 64 + lane] = make_float2(av, au);
    if (lane == 0) A.sc[c] = make_float2(svs, sus);
}

// ---------- K4b: wave-parallel forward-exclusive scans (65 tasks) ----------
__global__ __launch_bounds__(256) void k4b_scan(Args A) {
    int tid = threadIdx.x, wave = tid >> 6, lane = tid & 63;
    int task = blockIdx.x * 4 + wave;           // 17 blocks -> 68 waves
    if (task >= 65) return;
    const float2* src; float2* dst; int stride, col = 0;
    if (task < 64) { col = task; src = A.VU; dst = A.baseVU; stride = 64; }
    else           { src = A.sc; dst = A.basesc; stride = 1; }
    float bv = 0.f, bu = 0.f;
    for (int c0 = 0; c0 < NCHUNK; c0 += 64) {
        float2 xv = src[(c0 + lane) * stride + col];
        float iv = xv.x, iu = xv.y;
        #pragma unroll
        for (int off = 1; off < 64; off <<= 1) {
            float nv = __shfl_up(iv, off, 64);
            float nu = __shfl_up(iu, off, 64);
            if (lane >= off) { iv += nv; iu += nu; }
        }
        dst[(c0 + lane) * stride + col] = make_float2(bv + iv - xv.x, bu + iu - xv.y);
        bv += __shfl(iv, 63, 64);
        bu += __shfl(iu, 63, 64);
    }
    if (lane == 0) {
        if (task < 64) A.utot[task] = bu;       // U column total
        else           A.utots[0] = bu;         // U scalar total
    }
}

// ---------- K5: sweep with precomputed bases (384 blocks x 64) --------------
// Round-15 form: exp-hoist + keymask (branch still needed to pick the query
// path), __fdividef, __expf(r)-1 for expm1f.
__global__ __launch_bounds__(64) void k5_apply(Args A) {
    int lane = threadIdx.x;
    int c = blockIdx.x;                         // 384 chunks
    float T = A.Thdr[0];
    float myval = A.tfin[c * 64 + lane];
    int myid = A.idfin[c * 64 + lane];
    float x[64];
    #pragma unroll
    for (int k = 0; k < 64; ++k) {              // 64 independent gathers
        int uid = __shfl(myid, k, 64);
        x[k] = (uid < N) ? A.Wh[(size_t)uid * DOUT + lane] : 0.f;
    }
    float wvm = 0.f, wum = 0.f;
    if (myid < N) {
        wvm = __expf(0.2f * (myval - T));
        float w2 = wvm * wvm, w4 = w2 * w2;
        wum = w4 * wvm;                         // exp(myval-T) = wvm^5
    }
    unsigned long long keymask = __ballot(myid < N);
    float2 bvu = A.baseVU[c * 64 + lane];
    float2 bsc = A.basesc[c];
    float rv = bvu.x, ru = bvu.y, rvs = bsc.x, rus = bsc.y;
    float tu  = A.utot[lane];
    float tus = A.utots[0];
    #pragma unroll
    for (int k = 0; k < 64; ++k) {
        if ((keymask >> k) & 1) {               // key: advance running sums
            float wv = __shfl(wvm, k, 64);
            float wu = __shfl(wum, k, 64);
            rv = fmaf(wv, x[k], rv); ru = fmaf(wu, x[k], ru);
            rvs += wv; rus += wu;
        } else {                                // query: emit output row
            float uval = __shfl(myval, k, 64);
            int uid = __shfl(myid, k, 64);
            int i = uid - N;
            float xx = -uval + T;
            float mm = fmaxf(xx, 0.2f * xx);
            float cp_ = __expf(xx - mm);
            float cn_ = __expf(0.2f * xx - mm);
            float num = cn_ * rv + cp_ * (tu - ru);
            float den = cn_ * rvs + cp_ * (tus - rus);
            float r = __fdividef(num, den);
            A.out[(size_t)i * DOUT + lane] = r > 0.f ? r : (__expf(r) - 1.f);
        }
    }
}

extern "C" void kernel_launch(void* const* d_in, const int* in_sizes, int n_in,
                              void* d_out, int out_size, void* d_ws, size_t ws_size,
                              hipStream_t stream) {
    float* ws = (float*)d_ws;
    size_t o = 0;
    Args A;
    A.h = (const float*)d_in[0];
    A.W = (const float*)d_in[1];
    A.a = (const float*)d_in[2];
    A.out = (float*)d_out;
    A.Wh      = ws + o; o += (size_t)N * DOUT;
    A.s       = ws + o; o += N;
    A.t       = ws + o; o += N;
    A.tblkmax = ws + o; o += K1BLKS;            // 768 k1 blocks
    A.Thdr    = ws + o; o += 16;                // keeps o 16B-aligned
    A.vals64  = (unsigned long long*)(ws + o); o += 2 * (size_t)M;
    A.tfin    = ws + o; o += M;
    A.VU      = (float2*)(ws + o); o += 2 * (size_t)NCHUNK * DOUT;
    A.sc      = (float2*)(ws + o); o += 2 * NCHUNK;
    A.baseVU  = (float2*)(ws + o); o += 2 * (size_t)NCHUNK * DOUT;
    A.basesc  = (float2*)(ws + o); o += 2 * NCHUNK;
    A.utot    = ws + o; o += DOUT;
    A.utots   = ws + o; o += 16;
    A.idfin    = (int*)(ws + o); o += M;
    A.binstart = (int*)(ws + o); o += NBIN + 16;
    // ~4.1 MB total; no initialization required

    k1_gemm <<<K1BLKS, 256, 0, stream>>>(A);
    k2_sort <<<24, 1024, 0, stream>>>(A);
    k3_rank <<<M / 32, 256, 0, stream>>>(A);
    k4_sums <<<NCHUNK, 64, 0, stream>>>(A);
    k4b_scan<<<17, 256, 0, stream>>>(A);
    k5_apply<<<NCHUNK, 64, 0, stream>>>(A);
}

// Round 17
// 104.043 us; speedup vs baseline: 1.3600x; 1.0159x over previous
//
#include <hip/hip_runtime.h>

#define N 12288
#define M (2 * N)          // keys (t_j) + queries (-s_i)
#define DIN 128
#define DOUT 64
#define NBIN 8192
#define BSHIFT 19          // 32 - log2(NBIN)
#define NCHUNK 384         // M / 64
#define K1BLKS 768         // N / 16

// monotone float -> ordered u32 (order-preserving bit transform)
__device__ __forceinline__ unsigned f_ord(float x) {
    unsigned b = __float_as_uint(x);
    return (b & 0x80000000u) ? ~b : (b | 0x80000000u);
}
__device__ __forceinline__ float ord_f(unsigned u) {
    unsigned b = (u & 0x80000000u) ? (u & 0x7FFFFFFFu) : ~u;
    return __uint_as_float(b);
}
__device__ __forceinline__ int t_bin(float x) { return (int)(f_ord(x) >> BSHIFT); }

struct Args {
    const float *h, *W, *a;
    float *Wh, *s, *t, *tblkmax, *Thdr;
    unsigned long long *vals64;     // (ordered(val)<<32)|pi — unique total order
    float *tfin;
    int *idfin, *binstart;
    float2 *VU, *sc;                // per-chunk column/scalar sums {v,u}
    float2 *baseVU, *basesc;        // forward-exclusive prefixes
    float *utot, *utots;            // U totals (suffix = total - prefix)
    float *out;
};

// ---------- K1: Wh = h@W, s, t, per-block max(t) (768 blocks x 256) ---------
// 1 row x 4 cols per thread -> 3072 waves (3/SIMD, 12/CU); LDS 41 KB/block;
// h-tile stride padded 32->33 float4. Proven in round 9 (132.9 -> 127.1).
__global__ __launch_bounds__(256) void k1_gemm(Args A) {
    __shared__ float4 sm4[2576];               // 41 KB: W 2048 + h 16x33
    __shared__ float wmax[4];
    int tid = threadIdx.x, lane = tid & 63, wave = tid >> 6, blk = blockIdx.x;
    float4* Ws4 = sm4;                         // W[k][c4]  (2048)
    float4* hs4 = sm4 + 2048;                  // h[r][k4]  stride 33
    const float4* W4 = (const float4*)A.W;
    #pragma unroll
    for (int e = tid; e < 2048; e += 256) Ws4[e] = W4[e];
    int row0 = blk * 16;
    const float4* h4 = (const float4*)(A.h + (size_t)row0 * DIN);
    #pragma unroll
    for (int e = tid; e < 512; e += 256) hs4[(e >> 5) * 33 + (e & 31)] = h4[e];
    __syncthreads();
    int c0 = tid & 15, r = tid >> 4;           // 16 rows x 16 col-groups
    float4 acc = make_float4(0.f, 0.f, 0.f, 0.f);
    #pragma unroll 4
    for (int kk = 0; kk < 32; ++kk) {
        float4 hv = hs4[r * 33 + kk];          // broadcast among 16 lanes
        float4 w0 = Ws4[(4 * kk + 0) * 16 + c0];
        float4 w1 = Ws4[(4 * kk + 1) * 16 + c0];
        float4 w2 = Ws4[(4 * kk + 2) * 16 + c0];
        float4 w3 = Ws4[(4 * kk + 3) * 16 + c0];
        acc.x = fmaf(hv.x, w0.x, acc.x); acc.y = fmaf(hv.x, w0.y, acc.y);
        acc.z = fmaf(hv.x, w0.z, acc.z); acc.w = fmaf(hv.x, w0.w, acc.w);
        acc.x = fmaf(hv.y, w1.x, acc.x); acc.y = fmaf(hv.y, w1.y, acc.y);
        acc.z = fmaf(hv.y, w1.z, acc.z); acc.w = fmaf(hv.y, w1.w, acc.w);
        acc.x = fmaf(hv.z, w2.x, acc.x); acc.y = fmaf(hv.z, w2.y, acc.y);
        acc.z = fmaf(hv.z, w2.z, acc.z); acc.w = fmaf(hv.z, w2.w, acc.w);
        acc.x = fmaf(hv.w, w3.x, acc.x); acc.y = fmaf(hv.w, w3.y, acc.y);
        acc.z = fmaf(hv.w, w3.z, acc.z); acc.w = fmaf(hv.w, w3.w, acc.w);
    }
    int row = row0 + r;
    ((float4*)A.Wh)[(size_t)row * 16 + c0] = acc;
    float4 a1 = ((const float4*)A.a)[c0];
    float4 a2 = ((const float4*)A.a)[16 + c0];
    float sv = acc.x * a1.x + acc.y * a1.y + acc.z * a1.z + acc.w * a1.w;
    float tv = acc.x * a2.x + acc.y * a2.y + acc.z * a2.z + acc.w * a2.w;
    #pragma unroll
    for (int off = 8; off; off >>= 1) {        // reduce over 16-lane row group
        sv += __shfl_xor(sv, off, 64);
        tv += __shfl_xor(tv, off, 64);
    }
    if (c0 == 0) { A.s[row] = sv; A.t[row] = tv; }
    float tmax = tv;                           // every lane has its row's tv
    tmax = fmaxf(tmax, __shfl_xor(tmax, 16, 64));
    tmax = fmaxf(tmax, __shfl_xor(tmax, 32, 64));
    if (lane == 0) wmax[wave] = tmax;
    __syncthreads();
    if (tid == 0)
        A.tblkmax[blk] = fmaxf(fmaxf(wmax[0], wmax[1]), fmaxf(wmax[2], wmax[3]));
}

// ---------- K2: float4 hist pass + split-hist + scan + T + scatter ----------
// Round-16 form: float4 full-M pass (6 iters/thread), 2-way wave-parity hist
// split, merged pre-hist (quad-predicated), exact.
__global__ __launch_bounds__(1024) void k2_sort(Args A) {
    __shared__ int hist0[NBIN];                 // 32 KB
    __shared__ int hist1[NBIN];                 // 32 KB
    __shared__ int pre[NBIN];                   // 32 KB
    __shared__ int wtot[16];
    __shared__ float fmax_[16];
    int tid = threadIdx.x, lane = tid & 63, wave = tid >> 6, blk = blockIdx.x;
    #pragma unroll
    for (int e = tid; e < NBIN; e += 1024) { hist0[e] = 0; hist1[e] = 0; pre[e] = 0; }
    __syncthreads();
    int my0 = blk * 1024;
    int* myhist = (wave & 1) ? hist1 : hist0;
    #pragma unroll
    for (int it = 0; it < 6; ++it) {
        int qi = it * 1024 + tid;               // quad index; covers M/4 quads
        int e4 = qi * 4;                        // first element of the quad
        float4 v4;
        if (it < 3) {
            v4 = ((const float4*)A.t)[qi];
        } else {
            float4 s4 = ((const float4*)A.s)[qi - 3072];
            v4 = make_float4(-s4.x, -s4.y, -s4.z, -s4.w);
        }
        int ba = t_bin(v4.x), bb = t_bin(v4.y), bc = t_bin(v4.z), bd = t_bin(v4.w);
        atomicAdd(&myhist[ba], 1); atomicAdd(&myhist[bb], 1);
        atomicAdd(&myhist[bc], 1); atomicAdd(&myhist[bd], 1);
        if (e4 < my0) {                         // quad fully before my0 (4 | my0)
            atomicAdd(&pre[ba], 1); atomicAdd(&pre[bb], 1);
            atomicAdd(&pre[bc], 1); atomicAdd(&pre[bd], 1);
        }
    }
    __syncthreads();
    int b0 = tid * 8;
    int c8[8]; int sum = 0;
    #pragma unroll
    for (int g = 0; g < 8; ++g) { c8[g] = sum; sum += hist0[b0 + g] + hist1[b0 + g]; }
    int inc = sum;
    #pragma unroll
    for (int off = 1; off < 64; off <<= 1) {
        int nb = __shfl_up(inc, off, 64);
        if (lane >= off) inc += nb;
    }
    if (lane == 63) wtot[wave] = inc;
    __syncthreads();
    int wbase = 0;
    #pragma unroll
    for (int w = 0; w < 16; ++w) wbase += (w < wave) ? wtot[w] : 0;
    int tstart = wbase + inc - sum;
    #pragma unroll
    for (int g = 0; g < 8; ++g) {
        int bs = tstart + c8[g];
        pre[b0 + g] += bs;
        A.binstart[b0 + g] = bs;                // benign duplicate across blocks
    }
    if (tid == 0 && blk == 0) A.binstart[NBIN] = M;
    float m = (tid < K1BLKS) ? A.tblkmax[tid] : -3.4e38f;   // 768 k1 blocks
    #pragma unroll
    for (int off = 32; off; off >>= 1) m = fmaxf(m, __shfl_xor(m, off, 64));
    if (lane == 0) fmax_[wave] = m;
    __syncthreads();
    if (tid == 0) {
        float mm = fmax_[0];
        #pragma unroll
        for (int w = 1; w < 16; ++w) mm = fmaxf(mm, fmax_[w]);
        A.Thdr[0] = mm;
    }
    __syncthreads();
    {   // exactly one item per thread (slice == blockDim)
        int e = my0 + tid;
        float v = (e < N) ? A.t[e] : -A.s[e - N];
        int pi = (e < N) ? (e + N) : (e - N);   // queries sort before equal keys
        int pos = atomicAdd(&pre[t_bin(v)], 1);
        A.vals64[pos] = ((unsigned long long)f_ord(v) << 32) | (unsigned)pi;
    }
}

// ---------- K3: exact in-bin rank, 16 THREADS per position ----------
// Round-17: subs 8 -> 16 (1536 blocks x 256, 16 positions/block). Wall time
// is set by the hottest bin's per-thread scan = len/subs; halved again.
__global__ __launch_bounds__(256) void k3_rank(Args A) {
    __shared__ int parts[256];
    int tid = threadIdx.x;
    int li = tid & 15, sub = tid >> 4;          // 16 positions x 16 subs
    int p = blockIdx.x * 16 + li;
    unsigned long long kp = A.vals64[p];
    int b = (int)(kp >> (32 + BSHIFT));
    int lo = A.binstart[b], hi = A.binstart[b + 1];
    int len = hi - lo;
    int qlen = (len + 15) >> 4;
    int qlo = lo + sub * qlen;
    if (qlo > hi) qlo = hi;
    int qhi = qlo + qlen;
    if (qhi > hi) qhi = hi;
    int cnt = 0;
    int q = qlo;
    while (q < qhi && (q & 3)) cnt += (int)(A.vals64[q++] < kp);
    int bend = q + ((qhi - q) & ~3);
    #pragma unroll 2
    for (; q < bend; q += 4) {
        ulonglong2 u0 = *(const ulonglong2*)&A.vals64[q];
        ulonglong2 u1 = *(const ulonglong2*)&A.vals64[q + 2];
        cnt += (int)(u0.x < kp) + (int)(u0.y < kp)
             + (int)(u1.x < kp) + (int)(u1.y < kp);
    }
    while (q < qhi) cnt += (int)(A.vals64[q++] < kp);
    parts[sub * 16 + li] = cnt;
    __syncthreads();
    if (sub == 0) {
        int tot = 0;
        #pragma unroll
        for (int s2 = 0; s2 < 16; ++s2) tot += parts[s2 * 16 + li];
        int pi = (int)(unsigned)(kp & 0xffffffffu);
        A.tfin[lo + tot] = ord_f((unsigned)(kp >> 32));
        A.idfin[lo + tot] = (pi >= N) ? (pi - N) : (pi + N);
    }
}

// ---------- K4: per-chunk (64 sorted items) key-sums (384 blocks x 64) ------
// Round-17: gather+sweep fused into ONE loop (x[] staging array dropped).
// k4 is a plain chunk sum (no prefix semantics), so the fused accumulation
// order is bit-identical; after unrolling the 64 loads remain independent
// (same pipelining freedom), while the second 64-iter shfl pass disappears.
__global__ __launch_bounds__(64) void k4_sums(Args A) {
    int lane = threadIdx.x;
    int c = blockIdx.x;                         // 384 chunks
    float T = A.Thdr[0];
    float myval = A.tfin[c * 64 + lane];
    int myid = A.idfin[c * 64 + lane];
    float wvm = 0.f, wum = 0.f;
    if (myid < N) {
        wvm = __expf(0.2f * (myval - T));
        float w2 = wvm * wvm, w4 = w2 * w2;
        wum = w4 * wvm;                         // exp(myval-T) = wvm^5
    }
    float av = 0.f, au = 0.f, svs = 0.f, sus = 0.f;
    #pragma unroll
    for (int k = 0; k < 64; ++k) {
        int uid = __shfl(myid, k, 64);
        float xv = (uid < N) ? A.Wh[(size_t)uid * DOUT + lane] : 0.f;
        float wv = __shfl(wvm, k, 64);
        float wu = __shfl(wum, k, 64);
        av = fmaf(wv, xv, av); au = fmaf(wu, xv, au);
        svs += wv; sus += wu;
    }
    A.VU[c * 64 + lane] = make_float2(av, au);
    if (lane == 0) A.sc[c] = make_float2(svs, sus);
}

// ---------- K4b: wave-parallel forward-exclusive scans (65 tasks) ----------
__global__ __launch_bounds__(256) void k4b_scan(Args A) {
    int tid = threadIdx.x, wave = tid >> 6, lane = tid & 63;
    int task = blockIdx.x * 4 + wave;           // 17 blocks -> 68 waves
    if (task >= 65) return;
    const float2* src; float2* dst; int stride, col = 0;
    if (task < 64) { col = task; src = A.VU; dst = A.baseVU; stride = 64; }
    else           { src = A.sc; dst = A.basesc; stride = 1; }
    float bv = 0.f, bu = 0.f;
    for (int c0 = 0; c0 < NCHUNK; c0 += 64) {
        float2 xv = src[(c0 + lane) * stride + col];
        float iv = xv.x, iu = xv.y;
        #pragma unroll
        for (int off = 1; off < 64; off <<= 1) {
            float nv = __shfl_up(iv, off, 64);
            float nu = __shfl_up(iu, off, 64);
            if (lane >= off) { iv += nv; iu += nu; }
        }
        dst[(c0 + lane) * stride + col] = make_float2(bv + iv - xv.x, bu + iu - xv.y);
        bv += __shfl(iv, 63, 64);
        bu += __shfl(iu, 63, 64);
    }
    if (lane == 0) {
        if (task < 64) A.utot[task] = bu;       // U column total
        else           A.utots[0] = bu;         // U scalar total
    }
}

// ---------- K5: sweep with precomputed bases (384 blocks x 64) --------------
// Round-15 form: exp-hoist + keymask (branch still needed to pick the query
// path), __fdividef, __expf(r)-1 for expm1f. Two-pass (staged x[]) kept:
// the query branch consumes the running prefix, so the gather must stay
// decoupled to pipeline.
__global__ __launch_bounds__(64) void k5_apply(Args A) {
    int lane = threadIdx.x;
    int c = blockIdx.x;                         // 384 chunks
    float T = A.Thdr[0];
    float myval = A.tfin[c * 64 + lane];
    int myid = A.idfin[c * 64 + lane];
    float x[64];
    #pragma unroll
    for (int k = 0; k < 64; ++k) {              // 64 independent gathers
        int uid = __shfl(myid, k, 64);
        x[k] = (uid < N) ? A.Wh[(size_t)uid * DOUT + lane] : 0.f;
    }
    float wvm = 0.f, wum = 0.f;
    if (myid < N) {
        wvm = __expf(0.2f * (myval - T));
        float w2 = wvm * wvm, w4 = w2 * w2;
        wum = w4 * wvm;                         // exp(myval-T) = wvm^5
    }
    unsigned long long keymask = __ballot(myid < N);
    float2 bvu = A.baseVU[c * 64 + lane];
    float2 bsc = A.basesc[c];
    float rv = bvu.x, ru = bvu.y, rvs = bsc.x, rus = bsc.y;
    float tu  = A.utot[lane];
    float tus = A.utots[0];
    #pragma unroll
    for (int k = 0; k < 64; ++k) {
        if ((keymask >> k) & 1) {               // key: advance running sums
            float wv = __shfl(wvm, k, 64);
            float wu = __shfl(wum, k, 64);
            rv = fmaf(wv, x[k], rv); ru = fmaf(wu, x[k], ru);
            rvs += wv; rus += wu;
        } else {                                // query: emit output row
            float uval = __shfl(myval, k, 64);
            int uid = __shfl(myid, k, 64);
            int i = uid - N;
            float xx = -uval + T;
            float mm = fmaxf(xx, 0.2f * xx);
            float cp_ = __expf(xx - mm);
            float cn_ = __expf(0.2f * xx - mm);
            float num = cn_ * rv + cp_ * (tu - ru);
            float den = cn_ * rvs + cp_ * (tus - rus);
            float r = __fdividef(num, den);
            A.out[(size_t)i * DOUT + lane] = r > 0.f ? r : (__expf(r) - 1.f);
        }
    }
}

extern "C" void kernel_launch(void* const* d_in, const int* in_sizes, int n_in,
                              void* d_out, int out_size, void* d_ws, size_t ws_size,
                              hipStream_t stream) {
    float* ws = (float*)d_ws;
    size_t o = 0;
    Args A;
    A.h = (const float*)d_in[0];
    A.W = (const float*)d_in[1];
    A.a = (const float*)d_in[2];
    A.out = (float*)d_out;
    A.Wh      = ws + o; o += (size_t)N * DOUT;
    A.s       = ws + o; o += N;
    A.t       = ws + o; o += N;
    A.tblkmax = ws + o; o += K1BLKS;            // 768 k1 blocks
    A.Thdr    = ws + o; o += 16;                // keeps o 16B-aligned
    A.vals64  = (unsigned long long*)(ws + o); o += 2 * (size_t)M;
    A.tfin    = ws + o; o += M;
    A.VU      = (float2*)(ws + o); o += 2 * (size_t)NCHUNK * DOUT;
    A.sc      = (float2*)(ws + o); o += 2 * NCHUNK;
    A.baseVU  = (float2*)(ws + o); o += 2 * (size_t)NCHUNK * DOUT;
    A.basesc  = (float2*)(ws + o); o += 2 * NCHUNK;
    A.utot    = ws + o; o += DOUT;
    A.utots   = ws + o; o += 16;
    A.idfin    = (int*)(ws + o); o += M;
    A.binstart = (int*)(ws + o); o += NBIN + 16;
    // ~4.1 MB total; no initialization required

    k1_gemm <<<K1BLKS, 256, 0, stream>>>(A);
    k2_sort <<<24, 1024, 0, stream>>>(A);
    k3_rank <<<M / 16, 256, 0, stream>>>(A);
    k4_sums <<<NCHUNK, 64, 0, stream>>>(A);
    k4b_scan<<<17, 256, 0, stream>>>(A);
    k5_apply<<<NCHUNK, 64, 0, stream>>>(A);
}

// Round 18
// 101.630 us; speedup vs baseline: 1.3923x; 1.0237x over previous
//
#include <hip/hip_runtime.h>

#define N 12288
#define M (2 * N)          // keys (t_j) + queries (-s_i)
#define DIN 128
#define DOUT 64
#define NBIN 8192
#define BSHIFT 19          // 32 - log2(NBIN)
#define NCHUNK 384         // M / 64
#define K1BLKS 768         // N / 16

// monotone float -> ordered u32 (order-preserving bit transform)
__device__ __forceinline__ unsigned f_ord(float x) {
    unsigned b = __float_as_uint(x);
    return (b & 0x80000000u) ? ~b : (b | 0x80000000u);
}
__device__ __forceinline__ float ord_f(unsigned u) {
    unsigned b = (u & 0x80000000u) ? (u & 0x7FFFFFFFu) : ~u;
    return __uint_as_float(b);
}
__device__ __forceinline__ int t_bin(float x) { return (int)(f_ord(x) >> BSHIFT); }

struct Args {
    const float *h, *W, *a;
    float *Wh, *s, *t, *tblkmax, *Thdr;
    unsigned long long *vals64;     // (ordered(val)<<32)|pi — unique total order
    float *tfin;
    int *idfin, *binstart;
    float2 *VU, *sc;                // VU TRANSPOSED: [DOUT][NCHUNK] (round 18)
    float2 *baseVU, *basesc;        // baseVU transposed likewise
    float *utot, *utots;            // U totals (suffix = total - prefix)
    float *out;
};

// ---------- K1: Wh = h@W, s, t, per-block max(t) (768 blocks x 256) ---------
// 1 row x 4 cols per thread -> 3072 waves (3/SIMD, 12/CU); LDS 41 KB/block;
// h-tile stride padded 32->33 float4. Proven in round 9 (132.9 -> 127.1).
__global__ __launch_bounds__(256) void k1_gemm(Args A) {
    __shared__ float4 sm4[2576];               // 41 KB: W 2048 + h 16x33
    __shared__ float wmax[4];
    int tid = threadIdx.x, lane = tid & 63, wave = tid >> 6, blk = blockIdx.x;
    float4* Ws4 = sm4;                         // W[k][c4]  (2048)
    float4* hs4 = sm4 + 2048;                  // h[r][k4]  stride 33
    const float4* W4 = (const float4*)A.W;
    #pragma unroll
    for (int e = tid; e < 2048; e += 256) Ws4[e] = W4[e];
    int row0 = blk * 16;
    const float4* h4 = (const float4*)(A.h + (size_t)row0 * DIN);
    #pragma unroll
    for (int e = tid; e < 512; e += 256) hs4[(e >> 5) * 33 + (e & 31)] = h4[e];
    __syncthreads();
    int c0 = tid & 15, r = tid >> 4;           // 16 rows x 16 col-groups
    float4 acc = make_float4(0.f, 0.f, 0.f, 0.f);
    #pragma unroll 4
    for (int kk = 0; kk < 32; ++kk) {
        float4 hv = hs4[r * 33 + kk];          // broadcast among 16 lanes
        float4 w0 = Ws4[(4 * kk + 0) * 16 + c0];
        float4 w1 = Ws4[(4 * kk + 1) * 16 + c0];
        float4 w2 = Ws4[(4 * kk + 2) * 16 + c0];
        float4 w3 = Ws4[(4 * kk + 3) * 16 + c0];
        acc.x = fmaf(hv.x, w0.x, acc.x); acc.y = fmaf(hv.x, w0.y, acc.y);
        acc.z = fmaf(hv.x, w0.z, acc.z); acc.w = fmaf(hv.x, w0.w, acc.w);
        acc.x = fmaf(hv.y, w1.x, acc.x); acc.y = fmaf(hv.y, w1.y, acc.y);
        acc.z = fmaf(hv.y, w1.z, acc.z); acc.w = fmaf(hv.y, w1.w, acc.w);
        acc.x = fmaf(hv.z, w2.x, acc.x); acc.y = fmaf(hv.z, w2.y, acc.y);
        acc.z = fmaf(hv.z, w2.z, acc.z); acc.w = fmaf(hv.z, w2.w, acc.w);
        acc.x = fmaf(hv.w, w3.x, acc.x); acc.y = fmaf(hv.w, w3.y, acc.y);
        acc.z = fmaf(hv.w, w3.z, acc.z); acc.w = fmaf(hv.w, w3.w, acc.w);
    }
    int row = row0 + r;
    ((float4*)A.Wh)[(size_t)row * 16 + c0] = acc;
    float4 a1 = ((const float4*)A.a)[c0];
    float4 a2 = ((const float4*)A.a)[16 + c0];
    float sv = acc.x * a1.x + acc.y * a1.y + acc.z * a1.z + acc.w * a1.w;
    float tv = acc.x * a2.x + acc.y * a2.y + acc.z * a2.z + acc.w * a2.w;
    #pragma unroll
    for (int off = 8; off; off >>= 1) {        // reduce over 16-lane row group
        sv += __shfl_xor(sv, off, 64);
        tv += __shfl_xor(tv, off, 64);
    }
    if (c0 == 0) { A.s[row] = sv; A.t[row] = tv; }
    float tmax = tv;                           // every lane has its row's tv
    tmax = fmaxf(tmax, __shfl_xor(tmax, 16, 64));
    tmax = fmaxf(tmax, __shfl_xor(tmax, 32, 64));
    if (lane == 0) wmax[wave] = tmax;
    __syncthreads();
    if (tid == 0)
        A.tblkmax[blk] = fmaxf(fmaxf(wmax[0], wmax[1]), fmaxf(wmax[2], wmax[3]));
}

// ---------- K2: float4 hist pass + split-hist + scan + T + scatter ----------
// Round-16 form: float4 full-M pass (6 iters/thread), 2-way wave-parity hist
// split, merged pre-hist (quad-predicated), exact.
__global__ __launch_bounds__(1024) void k2_sort(Args A) {
    __shared__ int hist0[NBIN];                 // 32 KB
    __shared__ int hist1[NBIN];                 // 32 KB
    __shared__ int pre[NBIN];                   // 32 KB
    __shared__ int wtot[16];
    __shared__ float fmax_[16];
    int tid = threadIdx.x, lane = tid & 63, wave = tid >> 6, blk = blockIdx.x;
    #pragma unroll
    for (int e = tid; e < NBIN; e += 1024) { hist0[e] = 0; hist1[e] = 0; pre[e] = 0; }
    __syncthreads();
    int my0 = blk * 1024;
    int* myhist = (wave & 1) ? hist1 : hist0;
    #pragma unroll
    for (int it = 0; it < 6; ++it) {
        int qi = it * 1024 + tid;               // quad index; covers M/4 quads
        int e4 = qi * 4;                        // first element of the quad
        float4 v4;
        if (it < 3) {
            v4 = ((const float4*)A.t)[qi];
        } else {
            float4 s4 = ((const float4*)A.s)[qi - 3072];
            v4 = make_float4(-s4.x, -s4.y, -s4.z, -s4.w);
        }
        int ba = t_bin(v4.x), bb = t_bin(v4.y), bc = t_bin(v4.z), bd = t_bin(v4.w);
        atomicAdd(&myhist[ba], 1); atomicAdd(&myhist[bb], 1);
        atomicAdd(&myhist[bc], 1); atomicAdd(&myhist[bd], 1);
        if (e4 < my0) {                         // quad fully before my0 (4 | my0)
            atomicAdd(&pre[ba], 1); atomicAdd(&pre[bb], 1);
            atomicAdd(&pre[bc], 1); atomicAdd(&pre[bd], 1);
        }
    }
    __syncthreads();
    int b0 = tid * 8;
    int c8[8]; int sum = 0;
    #pragma unroll
    for (int g = 0; g < 8; ++g) { c8[g] = sum; sum += hist0[b0 + g] + hist1[b0 + g]; }
    int inc = sum;
    #pragma unroll
    for (int off = 1; off < 64; off <<= 1) {
        int nb = __shfl_up(inc, off, 64);
        if (lane >= off) inc += nb;
    }
    if (lane == 63) wtot[wave] = inc;
    __syncthreads();
    int wbase = 0;
    #pragma unroll
    for (int w = 0; w < 16; ++w) wbase += (w < wave) ? wtot[w] : 0;
    int tstart = wbase + inc - sum;
    #pragma unroll
    for (int g = 0; g < 8; ++g) {
        int bs = tstart + c8[g];
        pre[b0 + g] += bs;
        A.binstart[b0 + g] = bs;                // benign duplicate across blocks
    }
    if (tid == 0 && blk == 0) A.binstart[NBIN] = M;
    float m = (tid < K1BLKS) ? A.tblkmax[tid] : -3.4e38f;   // 768 k1 blocks
    #pragma unroll
    for (int off = 32; off; off >>= 1) m = fmaxf(m, __shfl_xor(m, off, 64));
    if (lane == 0) fmax_[wave] = m;
    __syncthreads();
    if (tid == 0) {
        float mm = fmax_[0];
        #pragma unroll
        for (int w = 1; w < 16; ++w) mm = fmaxf(mm, fmax_[w]);
        A.Thdr[0] = mm;
    }
    __syncthreads();
    {   // exactly one item per thread (slice == blockDim)
        int e = my0 + tid;
        float v = (e < N) ? A.t[e] : -A.s[e - N];
        int pi = (e < N) ? (e + N) : (e - N);   // queries sort before equal keys
        int pos = atomicAdd(&pre[t_bin(v)], 1);
        A.vals64[pos] = ((unsigned long long)f_ord(v) << 32) | (unsigned)pi;
    }
}

// ---------- K3: exact in-bin rank, 16 THREADS per position ----------
__global__ __launch_bounds__(256) void k3_rank(Args A) {
    __shared__ int parts[256];
    int tid = threadIdx.x;
    int li = tid & 15, sub = tid >> 4;          // 16 positions x 16 subs
    int p = blockIdx.x * 16 + li;
    unsigned long long kp = A.vals64[p];
    int b = (int)(kp >> (32 + BSHIFT));
    int lo = A.binstart[b], hi = A.binstart[b + 1];
    int len = hi - lo;
    int qlen = (len + 15) >> 4;
    int qlo = lo + sub * qlen;
    if (qlo > hi) qlo = hi;
    int qhi = qlo + qlen;
    if (qhi > hi) qhi = hi;
    int cnt = 0;
    int q = qlo;
    while (q < qhi && (q & 3)) cnt += (int)(A.vals64[q++] < kp);
    int bend = q + ((qhi - q) & ~3);
    #pragma unroll 2
    for (; q < bend; q += 4) {
        ulonglong2 u0 = *(const ulonglong2*)&A.vals64[q];
        ulonglong2 u1 = *(const ulonglong2*)&A.vals64[q + 2];
        cnt += (int)(u0.x < kp) + (int)(u0.y < kp)
             + (int)(u1.x < kp) + (int)(u1.y < kp);
    }
    while (q < qhi) cnt += (int)(A.vals64[q++] < kp);
    parts[sub * 16 + li] = cnt;
    __syncthreads();
    if (sub == 0) {
        int tot = 0;
        #pragma unroll
        for (int s2 = 0; s2 < 16; ++s2) tot += parts[s2 * 16 + li];
        int pi = (int)(unsigned)(kp & 0xffffffffu);
        A.tfin[lo + tot] = ord_f((unsigned)(kp >> 32));
        A.idfin[lo + tot] = (pi >= N) ? (pi - N) : (pi + N);
    }
}

// ---------- K4: per-chunk (64 sorted items) key-sums (384 blocks x 64) ------
// Round-18: VU write transposed to [DOUT][NCHUNK] — one uncoalesced
// fire-and-forget store per thread (store buffer absorbs it) in exchange
// for coalesced k4b column access. Values bit-identical.
__global__ __launch_bounds__(64) void k4_sums(Args A) {
    int lane = threadIdx.x;
    int c = blockIdx.x;                         // 384 chunks
    float T = A.Thdr[0];
    float myval = A.tfin[c * 64 + lane];
    int myid = A.idfin[c * 64 + lane];
    float wvm = 0.f, wum = 0.f;
    if (myid < N) {
        wvm = __expf(0.2f * (myval - T));
        float w2 = wvm * wvm, w4 = w2 * w2;
        wum = w4 * wvm;                         // exp(myval-T) = wvm^5
    }
    float av = 0.f, au = 0.f, svs = 0.f, sus = 0.f;
    #pragma unroll
    for (int k = 0; k < 64; ++k) {
        int uid = __shfl(myid, k, 64);
        float xv = (uid < N) ? A.Wh[(size_t)uid * DOUT + lane] : 0.f;
        float wv = __shfl(wvm, k, 64);
        float wu = __shfl(wum, k, 64);
        av = fmaf(wv, xv, av); au = fmaf(wu, xv, au);
        svs += wv; sus += wu;
    }
    A.VU[(size_t)lane * NCHUNK + c] = make_float2(av, au);   // transposed
    if (lane == 0) A.sc[c] = make_float2(svs, sus);
}

// ---------- K4b: wave-parallel forward-exclusive scans (65 tasks) ----------
// Round-18: with VU transposed, every task (column AND scalar) accesses a
// CONTIGUOUS [NCHUNK] run -> coalesced loads/stores (was stride-512B: 64
// cache lines per wave-op). All 6 batch loads hoisted into registers before
// the carry-dependent scan -> one L2 latency exposure instead of six.
__global__ __launch_bounds__(256) void k4b_scan(Args A) {
    int tid = threadIdx.x, wave = tid >> 6, lane = tid & 63;
    int task = blockIdx.x * 4 + wave;           // 17 blocks -> 68 waves
    if (task >= 65) return;
    const float2* srcp; float2* dstp;
    if (task < 64) { srcp = A.VU + (size_t)task * NCHUNK; dstp = A.baseVU + (size_t)task * NCHUNK; }
    else           { srcp = A.sc;                          dstp = A.basesc; }
    float2 xs[6];
    #pragma unroll
    for (int b = 0; b < 6; ++b) xs[b] = srcp[b * 64 + lane];   // 6 loads in flight
    float bv = 0.f, bu = 0.f;
    #pragma unroll
    for (int b = 0; b < 6; ++b) {
        float iv = xs[b].x, iu = xs[b].y;
        #pragma unroll
        for (int off = 1; off < 64; off <<= 1) {
            float nv = __shfl_up(iv, off, 64);
            float nu = __shfl_up(iu, off, 64);
            if (lane >= off) { iv += nv; iu += nu; }
        }
        dstp[b * 64 + lane] = make_float2(bv + iv - xs[b].x, bu + iu - xs[b].y);
        bv += __shfl(iv, 63, 64);
        bu += __shfl(iu, 63, 64);
    }
    if (lane == 0) {
        if (task < 64) A.utot[task] = bu;       // U column total
        else           A.utots[0] = bu;         // U scalar total
    }
}

// ---------- K5: sweep with precomputed bases (384 blocks x 64) --------------
// Round-18: baseVU read transposed — one uncoalesced load per thread,
// latency absorbed under the x[] gather. Otherwise round-15 form.
__global__ __launch_bounds__(64) void k5_apply(Args A) {
    int lane = threadIdx.x;
    int c = blockIdx.x;                         // 384 chunks
    float T = A.Thdr[0];
    float myval = A.tfin[c * 64 + lane];
    int myid = A.idfin[c * 64 + lane];
    float2 bvu = A.baseVU[(size_t)lane * NCHUNK + c];   // transposed; issue early
    float x[64];
    #pragma unroll
    for (int k = 0; k < 64; ++k) {              // 64 independent gathers
        int uid = __shfl(myid, k, 64);
        x[k] = (uid < N) ? A.Wh[(size_t)uid * DOUT + lane] : 0.f;
    }
    float wvm = 0.f, wum = 0.f;
    if (myid < N) {
        wvm = __expf(0.2f * (myval - T));
        float w2 = wvm * wvm, w4 = w2 * w2;
        wum = w4 * wvm;                         // exp(myval-T) = wvm^5
    }
    unsigned long long keymask = __ballot(myid < N);
    float2 bsc = A.basesc[c];
    float rv = bvu.x, ru = bvu.y, rvs = bsc.x, rus = bsc.y;
    float tu  = A.utot[lane];
    float tus = A.utots[0];
    #pragma unroll
    for (int k = 0; k < 64; ++k) {
        if ((keymask >> k) & 1) {               // key: advance running sums
            float wv = __shfl(wvm, k, 64);
            float wu = __shfl(wum, k, 64);
            rv = fmaf(wv, x[k], rv); ru = fmaf(wu, x[k], ru);
            rvs += wv; rus += wu;
        } else {                                // query: emit output row
            float uval = __shfl(myval, k, 64);
            int uid = __shfl(myid, k, 64);
            int i = uid - N;
            float xx = -uval + T;
            float mm = fmaxf(xx, 0.2f * xx);
            float cp_ = __expf(xx - mm);
            float cn_ = __expf(0.2f * xx - mm);
            float num = cn_ * rv + cp_ * (tu - ru);
            float den = cn_ * rvs + cp_ * (tus - rus);
            float r = __fdividef(num, den);
            A.out[(size_t)i * DOUT + lane] = r > 0.f ? r : (__expf(r) - 1.f);
        }
    }
}

extern "C" void kernel_launch(void* const* d_in, const int* in_sizes, int n_in,
                              void* d_out, int out_size, void* d_ws, size_t ws_size,
                              hipStream_t stream) {
    float* ws = (float*)d_ws;
    size_t o = 0;
    Args A;
    A.h = (const float*)d_in[0];
    A.W = (const float*)d_in[1];
    A.a = (const float*)d_in[2];
    A.out = (float*)d_out;
    A.Wh      = ws + o; o += (size_t)N * DOUT;
    A.s       = ws + o; o += N;
    A.t       = ws + o; o += N;
    A.tblkmax = ws + o; o += K1BLKS;            // 768 k1 blocks
    A.Thdr    = ws + o; o += 16;                // keeps o 16B-aligned
    A.vals64  = (unsigned long long*)(ws + o); o += 2 * (size_t)M;
    A.tfin    = ws + o; o += M;
    A.VU      = (float2*)(ws + o); o += 2 * (size_t)DOUT * NCHUNK;   // [DOUT][NCHUNK]
    A.sc      = (float2*)(ws + o); o += 2 * NCHUNK;
    A.baseVU  = (float2*)(ws + o); o += 2 * (size_t)DOUT * NCHUNK;   // [DOUT][NCHUNK]
    A.basesc  = (float2*)(ws + o); o += 2 * NCHUNK;
    A.utot    = ws + o; o += DOUT;
    A.utots   = ws + o; o += 16;
    A.idfin    = (int*)(ws + o); o += M;
    A.binstart = (int*)(ws + o); o += NBIN + 16;
    // ~4.1 MB total; no initialization required

    k1_gemm <<<K1BLKS, 256, 0, stream>>>(A);
    k2_sort <<<24, 1024, 0, stream>>>(A);
    k3_rank <<<M / 16, 256, 0, stream>>>(A);
    k4_sums <<<NCHUNK, 64, 0, stream>>>(A);
    k4b_scan<<<17, 256, 0, stream>>>(A);
    k5_apply<<<NCHUNK, 64, 0, stream>>>(A);
}

// Round 19
// 91.666 us; speedup vs baseline: 1.5436x; 1.1087x over previous
//
#include <hip/hip_runtime.h>

#define N 12288
#define M (2 * N)          // keys (t_j) + queries (-s_i)
#define DIN 128
#define DOUT 64
#define NBIN 8192
#define BSHIFT 19          // 32 - log2(NBIN)
#define NCHUNK 384         // M / 64
#define K1BLKS 768         // N / 16

// monotone float -> ordered u32 (order-preserving bit transform)
__device__ __forceinline__ unsigned f_ord(float x) {
    unsigned b = __float_as_uint(x);
    return (b & 0x80000000u) ? ~b : (b | 0x80000000u);
}
__device__ __forceinline__ float ord_f(unsigned u) {
    unsigned b = (u & 0x80000000u) ? (u & 0x7FFFFFFFu) : ~u;
    return __uint_as_float(b);
}
__device__ __forceinline__ int t_bin(float x) { return (int)(f_ord(x) >> BSHIFT); }

struct Args {
    const float *h, *W, *a;
    float *Wh, *s, *t, *tblkmax, *Thdr;
    unsigned long long *vals64;     // (ordered(val)<<32)|pi — unique total order
    float *tfin;
    int *idfin, *binstart;
    float2 *VU, *sc;                // VU TRANSPOSED: [DOUT][NCHUNK] (round 18)
    float2 *baseVU, *basesc;        // baseVU transposed likewise
    float *utot, *utots;            // U totals (suffix = total - prefix)
    float *out;
};

// ---------- K1: Wh = h@W, s, t, per-block max(t) (768 blocks x 256) ---------
// 1 row x 4 cols per thread -> 3072 waves (3/SIMD, 12/CU); LDS 41 KB/block;
// h-tile stride padded 32->33 float4. Proven in round 9 (132.9 -> 127.1).
__global__ __launch_bounds__(256) void k1_gemm(Args A) {
    __shared__ float4 sm4[2576];               // 41 KB: W 2048 + h 16x33
    __shared__ float wmax[4];
    int tid = threadIdx.x, lane = tid & 63, wave = tid >> 6, blk = blockIdx.x;
    float4* Ws4 = sm4;                         // W[k][c4]  (2048)
    float4* hs4 = sm4 + 2048;                  // h[r][k4]  stride 33
    const float4* W4 = (const float4*)A.W;
    #pragma unroll
    for (int e = tid; e < 2048; e += 256) Ws4[e] = W4[e];
    int row0 = blk * 16;
    const float4* h4 = (const float4*)(A.h + (size_t)row0 * DIN);
    #pragma unroll
    for (int e = tid; e < 512; e += 256) hs4[(e >> 5) * 33 + (e & 31)] = h4[e];
    __syncthreads();
    int c0 = tid & 15, r = tid >> 4;           // 16 rows x 16 col-groups
    float4 acc = make_float4(0.f, 0.f, 0.f, 0.f);
    #pragma unroll 4
    for (int kk = 0; kk < 32; ++kk) {
        float4 hv = hs4[r * 33 + kk];          // broadcast among 16 lanes
        float4 w0 = Ws4[(4 * kk + 0) * 16 + c0];
        float4 w1 = Ws4[(4 * kk + 1) * 16 + c0];
        float4 w2 = Ws4[(4 * kk + 2) * 16 + c0];
        float4 w3 = Ws4[(4 * kk + 3) * 16 + c0];
        acc.x = fmaf(hv.x, w0.x, acc.x); acc.y = fmaf(hv.x, w0.y, acc.y);
        acc.z = fmaf(hv.x, w0.z, acc.z); acc.w = fmaf(hv.x, w0.w, acc.w);
        acc.x = fmaf(hv.y, w1.x, acc.x); acc.y = fmaf(hv.y, w1.y, acc.y);
        acc.z = fmaf(hv.y, w1.z, acc.z); acc.w = fmaf(hv.y, w1.w, acc.w);
        acc.x = fmaf(hv.z, w2.x, acc.x); acc.y = fmaf(hv.z, w2.y, acc.y);
        acc.z = fmaf(hv.z, w2.z, acc.z); acc.w = fmaf(hv.z, w2.w, acc.w);
        acc.x = fmaf(hv.w, w3.x, acc.x); acc.y = fmaf(hv.w, w3.y, acc.y);
        acc.z = fmaf(hv.w, w3.z, acc.z); acc.w = fmaf(hv.w, w3.w, acc.w);
    }
    int row = row0 + r;
    ((float4*)A.Wh)[(size_t)row * 16 + c0] = acc;
    float4 a1 = ((const float4*)A.a)[c0];
    float4 a2 = ((const float4*)A.a)[16 + c0];
    float sv = acc.x * a1.x + acc.y * a1.y + acc.z * a1.z + acc.w * a1.w;
    float tv = acc.x * a2.x + acc.y * a2.y + acc.z * a2.z + acc.w * a2.w;
    #pragma unroll
    for (int off = 8; off; off >>= 1) {        // reduce over 16-lane row group
        sv += __shfl_xor(sv, off, 64);
        tv += __shfl_xor(tv, off, 64);
    }
    if (c0 == 0) { A.s[row] = sv; A.t[row] = tv; }
    float tmax = tv;                           // every lane has its row's tv
    tmax = fmaxf(tmax, __shfl_xor(tmax, 16, 64));
    tmax = fmaxf(tmax, __shfl_xor(tmax, 32, 64));
    if (lane == 0) wmax[wave] = tmax;
    __syncthreads();
    if (tid == 0)
        A.tblkmax[blk] = fmaxf(fmaxf(wmax[0], wmax[1]), fmaxf(wmax[2], wmax[3]));
}

// ---------- K2: float4 hist pass + split-hist + scan + T + scatter ----------
// Round-16 form: float4 full-M pass (6 iters/thread), 2-way wave-parity hist
// split, merged pre-hist (quad-predicated), exact.
__global__ __launch_bounds__(1024) void k2_sort(Args A) {
    __shared__ int hist0[NBIN];                 // 32 KB
    __shared__ int hist1[NBIN];                 // 32 KB
    __shared__ int pre[NBIN];                   // 32 KB
    __shared__ int wtot[16];
    __shared__ float fmax_[16];
    int tid = threadIdx.x, lane = tid & 63, wave = tid >> 6, blk = blockIdx.x;
    #pragma unroll
    for (int e = tid; e < NBIN; e += 1024) { hist0[e] = 0; hist1[e] = 0; pre[e] = 0; }
    __syncthreads();
    int my0 = blk * 1024;
    int* myhist = (wave & 1) ? hist1 : hist0;
    #pragma unroll
    for (int it = 0; it < 6; ++it) {
        int qi = it * 1024 + tid;               // quad index; covers M/4 quads
        int e4 = qi * 4;                        // first element of the quad
        float4 v4;
        if (it < 3) {
            v4 = ((const float4*)A.t)[qi];
        } else {
            float4 s4 = ((const float4*)A.s)[qi - 3072];
            v4 = make_float4(-s4.x, -s4.y, -s4.z, -s4.w);
        }
        int ba = t_bin(v4.x), bb = t_bin(v4.y), bc = t_bin(v4.z), bd = t_bin(v4.w);
        atomicAdd(&myhist[ba], 1); atomicAdd(&myhist[bb], 1);
        atomicAdd(&myhist[bc], 1); atomicAdd(&myhist[bd], 1);
        if (e4 < my0) {                         // quad fully before my0 (4 | my0)
            atomicAdd(&pre[ba], 1); atomicAdd(&pre[bb], 1);
            atomicAdd(&pre[bc], 1); atomicAdd(&pre[bd], 1);
        }
    }
    __syncthreads();
    int b0 = tid * 8;
    int c8[8]; int sum = 0;
    #pragma unroll
    for (int g = 0; g < 8; ++g) { c8[g] = sum; sum += hist0[b0 + g] + hist1[b0 + g]; }
    int inc = sum;
    #pragma unroll
    for (int off = 1; off < 64; off <<= 1) {
        int nb = __shfl_up(inc, off, 64);
        if (lane >= off) inc += nb;
    }
    if (lane == 63) wtot[wave] = inc;
    __syncthreads();
    int wbase = 0;
    #pragma unroll
    for (int w = 0; w < 16; ++w) wbase += (w < wave) ? wtot[w] : 0;
    int tstart = wbase + inc - sum;
    #pragma unroll
    for (int g = 0; g < 8; ++g) {
        int bs = tstart + c8[g];
        pre[b0 + g] += bs;
        A.binstart[b0 + g] = bs;                // benign duplicate across blocks
    }
    if (tid == 0 && blk == 0) A.binstart[NBIN] = M;
    float m = (tid < K1BLKS) ? A.tblkmax[tid] : -3.4e38f;   // 768 k1 blocks
    #pragma unroll
    for (int off = 32; off; off >>= 1) m = fmaxf(m, __shfl_xor(m, off, 64));
    if (lane == 0) fmax_[wave] = m;
    __syncthreads();
    if (tid == 0) {
        float mm = fmax_[0];
        #pragma unroll
        for (int w = 1; w < 16; ++w) mm = fmaxf(mm, fmax_[w]);
        A.Thdr[0] = mm;
    }
    __syncthreads();
    {   // exactly one item per thread (slice == blockDim)
        int e = my0 + tid;
        float v = (e < N) ? A.t[e] : -A.s[e - N];
        int pi = (e < N) ? (e + N) : (e - N);   // queries sort before equal keys
        int pos = atomicAdd(&pre[t_bin(v)], 1);
        A.vals64[pos] = ((unsigned long long)f_ord(v) << 32) | (unsigned)pi;
    }
}

// ---------- K3: exact in-bin rank, 16 THREADS per position ----------
__global__ __launch_bounds__(256) void k3_rank(Args A) {
    __shared__ int parts[256];
    int tid = threadIdx.x;
    int li = tid & 15, sub = tid >> 4;          // 16 positions x 16 subs
    int p = blockIdx.x * 16 + li;
    unsigned long long kp = A.vals64[p];
    int b = (int)(kp >> (32 + BSHIFT));
    int lo = A.binstart[b], hi = A.binstart[b + 1];
    int len = hi - lo;
    int qlen = (len + 15) >> 4;
    int qlo = lo + sub * qlen;
    if (qlo > hi) qlo = hi;
    int qhi = qlo + qlen;
    if (qhi > hi) qhi = hi;
    int cnt = 0;
    int q = qlo;
    while (q < qhi && (q & 3)) cnt += (int)(A.vals64[q++] < kp);
    int bend = q + ((qhi - q) & ~3);
    #pragma unroll 2
    for (; q < bend; q += 4) {
        ulonglong2 u0 = *(const ulonglong2*)&A.vals64[q];
        ulonglong2 u1 = *(const ulonglong2*)&A.vals64[q + 2];
        cnt += (int)(u0.x < kp) + (int)(u0.y < kp)
             + (int)(u1.x < kp) + (int)(u1.y < kp);
    }
    while (q < qhi) cnt += (int)(A.vals64[q++] < kp);
    parts[sub * 16 + li] = cnt;
    __syncthreads();
    if (sub == 0) {
        int tot = 0;
        #pragma unroll
        for (int s2 = 0; s2 < 16; ++s2) tot += parts[s2 * 16 + li];
        int pi = (int)(unsigned)(kp & 0xffffffffu);
        A.tfin[lo + tot] = ord_f((unsigned)(kp >> 32));
        A.idfin[lo + tot] = (pi >= N) ? (pi - N) : (pi + N);
    }
}

// ---------- K4: per-chunk key-sums, 4 WAVES per chunk (384 blocks x 256) ----
// Round-19: previous 384x64 config ran 384 waves on 1024 SIMDs (0.375/SIMD)
// with a fully-exposed 64-iter serial sweep. Now wave w sums items
// w*16..w*16+15 branchlessly (16 gathers + 16 fmaf) and wave 0 combines the
// 4 partials via LDS. 1536 waves (1.5/SIMD), serial loop 64 -> 16. FP
// re-association only (grouped partial adds) — ~1e-6 vs 7.8e-3 tolerance.
__global__ __launch_bounds__(256) void k4_sums(Args A) {
    __shared__ float2 part[4][64];
    __shared__ float2 scp[4];
    int tid = threadIdx.x, wave = tid >> 6, lane = tid & 63;
    int c = blockIdx.x;                         // 384 chunks
    float T = A.Thdr[0];
    float myval = A.tfin[c * 64 + lane];
    int myid = A.idfin[c * 64 + lane];
    float wvm = 0.f, wum = 0.f;
    if (myid < N) {
        wvm = __expf(0.2f * (myval - T));
        float w2 = wvm * wvm, w4 = w2 * w2;
        wum = w4 * wvm;                         // exp(myval-T) = wvm^5
    }
    float av = 0.f, au = 0.f, svs = 0.f, sus = 0.f;
    int k0 = wave * 16;
    #pragma unroll
    for (int kk = 0; kk < 16; ++kk) {
        int k = k0 + kk;
        int uid = __shfl(myid, k, 64);
        float xv = (uid < N) ? A.Wh[(size_t)uid * DOUT + lane] : 0.f;
        float wv = __shfl(wvm, k, 64);
        float wu = __shfl(wum, k, 64);
        av = fmaf(wv, xv, av); au = fmaf(wu, xv, au);
        svs += wv; sus += wu;
    }
    part[wave][lane] = make_float2(av, au);
    if (lane == 0) scp[wave] = make_float2(svs, sus);
    __syncthreads();
    if (wave == 0) {
        float2 p1 = part[1][lane], p2 = part[2][lane], p3 = part[3][lane];
        A.VU[(size_t)lane * NCHUNK + c] =
            make_float2(av + p1.x + p2.x + p3.x, au + p1.y + p2.y + p3.y);
        if (lane == 0) {
            float2 s1 = scp[1], s2 = scp[2], s3 = scp[3];
            A.sc[c] = make_float2(svs + s1.x + s2.x + s3.x,
                                  sus + s1.y + s2.y + s3.y);
        }
    }
}

// ---------- K4b: wave-parallel forward-exclusive scans (65 tasks) ----------
// Round-18 form: VU transposed -> contiguous coalesced runs; 6 batch loads
// hoisted into registers before the carry-dependent scan.
__global__ __launch_bounds__(256) void k4b_scan(Args A) {
    int tid = threadIdx.x, wave = tid >> 6, lane = tid & 63;
    int task = blockIdx.x * 4 + wave;           // 17 blocks -> 68 waves
    if (task >= 65) return;
    const float2* srcp; float2* dstp;
    if (task < 64) { srcp = A.VU + (size_t)task * NCHUNK; dstp = A.baseVU + (size_t)task * NCHUNK; }
    else           { srcp = A.sc;                          dstp = A.basesc; }
    float2 xs[6];
    #pragma unroll
    for (int b = 0; b < 6; ++b) xs[b] = srcp[b * 64 + lane];   // 6 loads in flight
    float bv = 0.f, bu = 0.f;
    #pragma unroll
    for (int b = 0; b < 6; ++b) {
        float iv = xs[b].x, iu = xs[b].y;
        #pragma unroll
        for (int off = 1; off < 64; off <<= 1) {
            float nv = __shfl_up(iv, off, 64);
            float nu = __shfl_up(iu, off, 64);
            if (lane >= off) { iv += nv; iu += nu; }
        }
        dstp[b * 64 + lane] = make_float2(bv + iv - xs[b].x, bu + iu - xs[b].y);
        bv += __shfl(iv, 63, 64);
        bu += __shfl(iu, 63, 64);
    }
    if (lane == 0) {
        if (task < 64) A.utot[task] = bu;       // U column total
        else           A.utots[0] = bu;         // U scalar total
    }
}

// ---------- K5: apply, 4 WAVES per chunk (384 blocks x 256) -----------------
// Round-19: wave w first computes its 16-item segment's branchless key
// partials (gathering x into 16 registers), publishes via LDS, syncs
// (intra-block only), then sweeps its segment starting from base +
// earlier-segment partials. Critical path 64 -> 16+16 iters; gather 64 -> 16
// loads/wave across 4 SIMDs. Prefix values identical up to FP grouping.
__global__ __launch_bounds__(256) void k5_apply(Args A) {
    __shared__ float2 part[4][64];
    __shared__ float2 scp[4];
    int tid = threadIdx.x, wave = tid >> 6, lane = tid & 63;
    int c = blockIdx.x;                         // 384 chunks
    float T = A.Thdr[0];
    float myval = A.tfin[c * 64 + lane];
    int myid = A.idfin[c * 64 + lane];
    float2 bvu = A.baseVU[(size_t)lane * NCHUNK + c];   // transposed; issue early
    float wvm = 0.f, wum = 0.f;
    if (myid < N) {
        wvm = __expf(0.2f * (myval - T));
        float w2 = wvm * wvm, w4 = w2 * w2;
        wum = w4 * wvm;                         // exp(myval-T) = wvm^5
    }
    unsigned long long keymask = __ballot(myid < N);
    int k0 = wave * 16;
    float x[16];
    float pav = 0.f, pau = 0.f, psv = 0.f, psu = 0.f;
    #pragma unroll
    for (int kk = 0; kk < 16; ++kk) {           // segment gather + key partials
        int k = k0 + kk;
        int uid = __shfl(myid, k, 64);
        x[kk] = (uid < N) ? A.Wh[(size_t)uid * DOUT + lane] : 0.f;
        float wv = __shfl(wvm, k, 64);
        float wu = __shfl(wum, k, 64);
        pav = fmaf(wv, x[kk], pav); pau = fmaf(wu, x[kk], pau);
        psv += wv; psu += wu;
    }
    part[wave][lane] = make_float2(pav, pau);
    if (lane == 0) scp[wave] = make_float2(psv, psu);
    __syncthreads();
    float2 bsc = A.basesc[c];
    float rv = bvu.x, ru = bvu.y, rvs = bsc.x, rus = bsc.y;
    #pragma unroll
    for (int w2 = 0; w2 < 3; ++w2) {            // add earlier segments' partials
        if (w2 < wave) {
            float2 p = part[w2][lane];
            float2 s = scp[w2];
            rv += p.x; ru += p.y; rvs += s.x; rus += s.y;
        }
    }
    float tu  = A.utot[lane];
    float tus = A.utots[0];
    #pragma unroll
    for (int kk = 0; kk < 16; ++kk) {
        int k = k0 + kk;
        if ((keymask >> k) & 1) {               // key: advance running sums
            float wv = __shfl(wvm, k, 64);
            float wu = __shfl(wum, k, 64);
            rv = fmaf(wv, x[kk], rv); ru = fmaf(wu, x[kk], ru);
            rvs += wv; rus += wu;
        } else {                                // query: emit output row
            float uval = __shfl(myval, k, 64);
            int uid = __shfl(myid, k, 64);
            int i = uid - N;
            float xx = -uval + T;
            float mm = fmaxf(xx, 0.2f * xx);
            float cp_ = __expf(xx - mm);
            float cn_ = __expf(0.2f * xx - mm);
            float num = cn_ * rv + cp_ * (tu - ru);
            float den = cn_ * rvs + cp_ * (tus - rus);
            float r = __fdividef(num, den);
            A.out[(size_t)i * DOUT + lane] = r > 0.f ? r : (__expf(r) - 1.f);
        }
    }
}

extern "C" void kernel_launch(void* const* d_in, const int* in_sizes, int n_in,
                              void* d_out, int out_size, void* d_ws, size_t ws_size,
                              hipStream_t stream) {
    float* ws = (float*)d_ws;
    size_t o = 0;
    Args A;
    A.h = (const float*)d_in[0];
    A.W = (const float*)d_in[1];
    A.a = (const float*)d_in[2];
    A.out = (float*)d_out;
    A.Wh      = ws + o; o += (size_t)N * DOUT;
    A.s       = ws + o; o += N;
    A.t       = ws + o; o += N;
    A.tblkmax = ws + o; o += K1BLKS;            // 768 k1 blocks
    A.Thdr    = ws + o; o += 16;                // keeps o 16B-aligned
    A.vals64  = (unsigned long long*)(ws + o); o += 2 * (size_t)M;
    A.tfin    = ws + o; o += M;
    A.VU      = (float2*)(ws + o); o += 2 * (size_t)DOUT * NCHUNK;   // [DOUT][NCHUNK]
    A.sc      = (float2*)(ws + o); o += 2 * NCHUNK;
    A.baseVU  = (float2*)(ws + o); o += 2 * (size_t)DOUT * NCHUNK;   // [DOUT][NCHUNK]
    A.basesc  = (float2*)(ws + o); o += 2 * NCHUNK;
    A.utot    = ws + o; o += DOUT;
    A.utots   = ws + o; o += 16;
    A.idfin    = (int*)(ws + o); o += M;
    A.binstart = (int*)(ws + o); o += NBIN + 16;
    // ~4.1 MB total; no initialization required

    k1_gemm <<<K1BLKS, 256, 0, stream>>>(A);
    k2_sort <<<24, 1024, 0, stream>>>(A);
    k3_rank <<<M / 16, 256, 0, stream>>>(A);
    k4_sums <<<NCHUNK, 256, 0, stream>>>(A);
    k4b_scan<<<17, 256, 0, stream>>>(A);
    k5_apply<<<NCHUNK, 256, 0, stream>>>(A);
}